// Round 1
// baseline (1008.505 us; speedup 1.0000x reference)
//
#include <hip/hip_runtime.h>
#include <hip/hip_bf16.h>
#include <math.h>

using bf16 = __hip_bfloat16;
typedef __bf16 bf16x8 __attribute__((ext_vector_type(8)));
typedef float f32x4 __attribute__((ext_vector_type(4)));

#define EPS16F 0.0009765625f

__device__ __forceinline__ float b2f(bf16 v){ return __bfloat162float(v); }
__device__ __forceinline__ bf16  f2b(float f){ return __float2bfloat16(f); }
__device__ __forceinline__ unsigned short f2bu(float f){
  bf16 h = __float2bfloat16(f); return __builtin_bit_cast(unsigned short, h);
}

__device__ __forceinline__ void gload16(const void* g, void* l){
  __builtin_amdgcn_global_load_lds((const __attribute__((address_space(1))) void*)g,
                                   (__attribute__((address_space(3))) void*)l, 16, 0, 0);
}

// ---------------- fp32 -> bf16 convert ----------------
__global__ void k_f2b(const float* __restrict__ in, bf16* __restrict__ out, int n){
  int i = (blockIdx.x*blockDim.x + threadIdx.x)*4;
  if (i + 3 < n){
    float4 v = *(const float4*)(in + i);
    ushort4 pk = make_ushort4(f2bu(v.x), f2bu(v.y), f2bu(v.z), f2bu(v.w));
    *reinterpret_cast<ushort4*>(out + i) = pk;
  } else {
    for (; i < n; ++i) out[i] = f2b(in[i]);
  }
}

// ---------------- LN1 stats: x (B,C,N) -> mu,rs per (b,n) ----------------
__global__ void k_ln1_stats(const float* __restrict__ x, float* __restrict__ mu,
                            float* __restrict__ rs){
  int b = blockIdx.y, n0 = blockIdx.x*64;
  int j = threadIdx.x & 63, cs = threadIdx.x >> 6;
  const float* xp = x + (size_t)b*1024*1024 + n0 + j;
  float s = 0.f, q = 0.f;
  for (int c = cs; c < 1024; c += 4){
    float v = xp[(size_t)c*1024];
    s += v; q += v*v;
  }
  __shared__ float ls[4][64], lq[4][64];
  ls[cs][j] = s; lq[cs][j] = q;
  __syncthreads();
  if (threadIdx.x < 64){
    int jj = threadIdx.x;
    float S = ls[0][jj]+ls[1][jj]+ls[2][jj]+ls[3][jj];
    float Q = lq[0][jj]+lq[1][jj]+lq[2][jj]+lq[3][jj];
    float m = S*(1.f/1024.f);
    float var = Q*(1.f/1024.f) - m*m;
    mu[b*1024 + n0 + jj] = m;
    rs[b*1024 + n0 + jj] = rsqrtf(var + 1e-5f);
  }
}

// ---------------- LN1 apply + transpose: -> Y3 (B,N,C) bf16 ----------------
__global__ void k_ln1_apply(const float* __restrict__ x, const float* __restrict__ mu,
                            const float* __restrict__ rs, const float* __restrict__ w,
                            const float* __restrict__ bias, bf16* __restrict__ y3){
  int b = blockIdx.z, c0 = blockIdx.y*64, n0 = blockIdx.x*64;
  __shared__ float t[64][65];   // [n_local][c_local]
  int j = threadIdx.x & 63, i0 = (threadIdx.x >> 6)*16;
  const float* xp = x + ((size_t)b*1024 + c0)*1024 + n0;
  #pragma unroll
  for (int r = 0; r < 16; ++r)
    t[j][i0 + r] = xp[(size_t)(i0 + r)*1024 + j];
  __syncthreads();
  int i = threadIdx.x & 63, jj0 = (threadIdx.x >> 6)*16;
  float wc = w[c0 + i], bc = bias[c0 + i];
  bf16* yp = y3 + ((size_t)b*1024 + n0)*1024 + c0 + i;
  #pragma unroll
  for (int r = 0; r < 16; ++r){
    int n = n0 + jj0 + r;
    float v = t[jj0 + r][i];
    yp[(size_t)(jj0 + r)*1024] = f2b((v - mu[b*1024 + n])*rs[b*1024 + n]*wc + bc);
  }
}

// ---------------- GEMM: out(M,N) = A(M,K) * W(N,K)^T, bf16 in/out ----------------
// EPI: 0 = plain, 1 = +bias +exact gelu, 2 = +bias
template<int EPI>
__global__ void __launch_bounds__(256) k_gemm(const bf16* __restrict__ A,
                                              const bf16* __restrict__ W,
                                              bf16* __restrict__ out,
                                              const float* __restrict__ bias,
                                              int M, int N, int K){
  __shared__ alignas(16) bf16 As[128*64];
  __shared__ alignas(16) bf16 Bs[128*64];
  int m0 = blockIdx.y*128, n0 = blockIdx.x*128;
  int t = threadIdx.x;
  int lane = t & 63, wave = t >> 6;
  int wr = wave >> 1, wc = wave & 1;      // 2x2 waves, each owns 64x64
  f32x4 acc[4][4] = {};
  int lr = lane & 15;
  int lg = lane >> 4;

  for (int k0 = 0; k0 < K; k0 += 64){
    #pragma unroll
    for (int i = 0; i < 4; ++i){
      int q = i*256 + t;
      int row = q >> 3, cq = q & 7;
      gload16(A + (size_t)(m0 + row)*K + k0 + cq*8, As + q*8);
      gload16(W + (size_t)(n0 + row)*K + k0 + cq*8, Bs + q*8);
    }
    __syncthreads();
    #pragma unroll
    for (int kk = 0; kk < 2; ++kk){
      int lk = lg*8 + kk*32;
      bf16x8 av[4], bv[4];
      #pragma unroll
      for (int m = 0; m < 4; ++m)
        av[m] = *reinterpret_cast<const bf16x8*>(As + (wr*64 + m*16 + lr)*64 + lk);
      #pragma unroll
      for (int n = 0; n < 4; ++n)
        bv[n] = *reinterpret_cast<const bf16x8*>(Bs + (wc*64 + n*16 + lr)*64 + lk);
      #pragma unroll
      for (int m = 0; m < 4; ++m)
        #pragma unroll
        for (int n = 0; n < 4; ++n)
          acc[m][n] = __builtin_amdgcn_mfma_f32_16x16x32_bf16(av[m], bv[n], acc[m][n], 0, 0, 0);
    }
    __syncthreads();
  }

  #pragma unroll
  for (int m = 0; m < 4; ++m){
    #pragma unroll
    for (int n = 0; n < 4; ++n){
      int col = n0 + wc*64 + n*16 + lr;
      #pragma unroll
      for (int j = 0; j < 4; ++j){
        int row = m0 + wr*64 + m*16 + lg*4 + j;
        float v = acc[m][n][j];
        if (EPI >= 1) v += bias[col];
        if (EPI == 1) v = 0.5f*v*(1.0f + erff(v*0.70710678118654752f));
        out[(size_t)row*N + col] = f2b(v);
      }
    }
  }
}

// ---------------- chunk partial sums of w^2 (optionally * Pi) ----------------
template<bool WEIGHTED>
__global__ void k_chunksum(const bf16* __restrict__ Wb, const float* __restrict__ Pi,
                           float* __restrict__ S){
  int blk = blockIdx.x;
  int ch = blk & 15, h = (blk >> 4) & 7, b = blk >> 7;
  int dd = threadIdx.x;
  const bf16* wp = Wb + ((size_t)(b*1024) + ch*64)*1024 + h*128 + dd;
  float acc = 0.f;
  #pragma unroll 8
  for (int i = 0; i < 64; ++i){
    float w = b2f(wp[(size_t)i*1024]);
    float sq = w*w;
    if (WEIGHTED) sq *= Pi[(size_t)(b*8 + h)*1024 + ch*64 + i];
    acc += sq;
  }
  S[(size_t)blk*128 + dd] = acc;
}

// ---------------- stage A: running denom -> tmp(b,h,n) ----------------
__global__ void k_stageA(const bf16* __restrict__ Wb, const float* __restrict__ S1,
                         const float* __restrict__ temp, const float* __restrict__ dbias,
                         float* __restrict__ tmp){
  int blk = blockIdx.x;
  int ch = blk & 15, h = (blk >> 4) & 7, b = blk >> 7;
  int dd = threadIdx.x;
  const float* sp = S1 + (size_t)(b*8 + h)*16*128 + dd;
  float base = 0.f;
  for (int c = 0; c < ch; ++c) base += sp[(size_t)c*128];
  __shared__ float V[64][129];
  const bf16* wp = Wb + ((size_t)(b*1024) + ch*64)*1024 + h*128 + dd;
  float run = base;
  for (int i = 0; i < 64; ++i){
    float w = b2f(wp[(size_t)i*1024]);
    float sq = w*w;
    run += sq;
    V[i][dd] = sq / fmaxf(run, EPS16F);
  }
  __syncthreads();
  int tt = threadIdx.x;
  int n_loc = tt >> 1, half = tt & 1;
  float s = 0.f;
  for (int k = 0; k < 64; ++k) s += V[n_loc][half*64 + k];
  s += __shfl_xor(s, 1);
  if (half == 0){
    int n = ch*64 + n_loc;
    float db = dbias[h*1024 + n];
    tmp[(size_t)(b*8 + h)*1024 + n] = (s + 128.f*db)*temp[h];
  }
}

// ---------------- softmax over heads + inclusive scan of Pi over n ----------------
__global__ void k_softmax_scan(const float* __restrict__ tmp, float* __restrict__ Pi,
                               float* __restrict__ Pc){
  int bh = blockIdx.x; int b = bh >> 3, h = bh & 7;
  int t = threadIdx.x;
  const float* tp = tmp + (size_t)b*8*1024;
  float p[4];
  #pragma unroll
  for (int i = 0; i < 4; ++i){
    int n = t*4 + i;
    float v[8]; float mx = -1e30f;
    #pragma unroll
    for (int hh = 0; hh < 8; ++hh){ v[hh] = tp[hh*1024 + n]; mx = fmaxf(mx, v[hh]); }
    float Z = 0.f;
    #pragma unroll
    for (int hh = 0; hh < 8; ++hh) Z += expf(v[hh] - mx);
    p[i] = expf(v[h] - mx)/Z;
    Pi[(size_t)bh*1024 + n] = p[i];
  }
  float l0 = p[0], l1 = l0 + p[1], l2 = l1 + p[2], l3 = l2 + p[3];
  float ts = l3, sc = ts;
  int ln = t & 63, wv = t >> 6;
  #pragma unroll
  for (int d = 1; d < 64; d <<= 1){
    float o = __shfl_up(sc, d);
    if (ln >= d) sc += o;
  }
  __shared__ float wsum[4];
  if (ln == 63) wsum[wv] = sc;
  __syncthreads();
  float woff = 0.f;
  for (int w2 = 0; w2 < 4; ++w2) if (w2 < wv) woff += wsum[w2];
  float excl = woff + sc - ts;
  size_t o4 = (size_t)bh*1024 + t*4;
  Pc[o4]   = excl + l0;
  Pc[o4+1] = excl + l1;
  Pc[o4+2] = excl + l2;
  Pc[o4+3] = excl + l3;
}

// ---------------- stage C: dots -> y (B,N,O) bf16 ----------------
__global__ void k_stageC(const bf16* __restrict__ Wb, const float* __restrict__ S2,
                         const float* __restrict__ Pi, const float* __restrict__ Pc,
                         bf16* __restrict__ Y){
  int blk = blockIdx.x;
  int ch = blk & 15, h = (blk >> 4) & 7, b = blk >> 7;
  int dd = threadIdx.x;
  const float* sp = S2 + (size_t)(b*8 + h)*16*128 + dd;
  float base = 0.f;
  for (int c = 0; c < ch; ++c) base += sp[(size_t)c*128];
  const bf16* wp = Wb + ((size_t)(b*1024) + ch*64)*1024 + h*128 + dd;
  bf16* yp = Y + ((size_t)(b*1024) + ch*64)*1024 + h*128 + dd;
  const float* pip = Pi + (size_t)(b*8 + h)*1024 + ch*64;
  const float* pcp = Pc + (size_t)(b*8 + h)*1024 + ch*64;
  float run = base;
  for (int i = 0; i < 64; ++i){
    float w = b2f(wp[(size_t)i*1024]);
    float sq = w*w;
    float pi = pip[i];
    run += sq*pi;
    float dots = run / (pcp[i] + EPS16F);
    float at = 1.0f/(1.0f + dots);
    yp[(size_t)i*1024] = f2b(-(w*pi)*at);
  }
}

// ---------------- residual 1: x1(B,N,C) = xT + g1 * a ----------------
__global__ void k_resid1(const float* __restrict__ x, const bf16* __restrict__ Ab,
                         const float* __restrict__ g1, float* __restrict__ x1){
  int b = blockIdx.z, c0 = blockIdx.y*64, n0 = blockIdx.x*64;
  __shared__ float t[64][65];   // [n_local][c_local]
  int j = threadIdx.x & 63, i0 = (threadIdx.x >> 6)*16;
  const float* xp = x + ((size_t)b*1024 + c0)*1024 + n0;
  #pragma unroll
  for (int r = 0; r < 16; ++r)
    t[j][i0 + r] = xp[(size_t)(i0 + r)*1024 + j];
  __syncthreads();
  int i = threadIdx.x & 63, jj0 = (threadIdx.x >> 6)*16;
  float g = g1[c0 + i];
  #pragma unroll
  for (int r = 0; r < 16; ++r){
    size_t off = ((size_t)b*1024 + n0 + jj0 + r)*1024 + c0 + i;
    x1[off] = t[jj0 + r][i] + g*b2f(Ab[off]);
  }
}

// ---------------- LN2 fused (row-contig) -> Y4 bf16 ----------------
__global__ void k_ln2(const float* __restrict__ x1, const float* __restrict__ w,
                      const float* __restrict__ bias, bf16* __restrict__ y4){
  int row = blockIdx.x, t = threadIdx.x;
  const float4* rp = (const float4*)(x1 + (size_t)row*1024);
  float4 v = rp[t];
  float s = v.x + v.y + v.z + v.w;
  float q = v.x*v.x + v.y*v.y + v.z*v.z + v.w*v.w;
  #pragma unroll
  for (int d = 32; d >= 1; d >>= 1){ s += __shfl_xor(s, d); q += __shfl_xor(q, d); }
  __shared__ float ss[4], qq[4];
  int wv = t >> 6, ln = t & 63;
  if (ln == 0){ ss[wv] = s; qq[wv] = q; }
  __syncthreads();
  s = ss[0] + ss[1] + ss[2] + ss[3];
  q = qq[0] + qq[1] + qq[2] + qq[3];
  float m = s*(1.f/1024.f);
  float var = q*(1.f/1024.f) - m*m;
  float r = rsqrtf(var + 1e-5f);
  int c = t*4;
  ushort4 pk = make_ushort4(
      f2bu((v.x - m)*r*w[c]   + bias[c]),
      f2bu((v.y - m)*r*w[c+1] + bias[c+1]),
      f2bu((v.z - m)*r*w[c+2] + bias[c+2]),
      f2bu((v.w - m)*r*w[c+3] + bias[c+3]));
  *reinterpret_cast<ushort4*>(y4 + (size_t)row*1024 + c) = pk;
}

// ---------------- residual 2 + transpose: out(B,C,N) = x1 + g2*m ----------------
__global__ void k_resid2(const float* __restrict__ x1, const bf16* __restrict__ Mb,
                         const float* __restrict__ g2, float* __restrict__ out){
  int b = blockIdx.z, c0 = blockIdx.y*64, n0 = blockIdx.x*64;
  __shared__ float t[64][65];   // [c_local][n_local]
  int i = threadIdx.x & 63, j0 = (threadIdx.x >> 6)*16;
  float g = g2[c0 + i];
  #pragma unroll
  for (int r = 0; r < 16; ++r){
    size_t off = ((size_t)b*1024 + n0 + j0 + r)*1024 + c0 + i;
    t[i][j0 + r] = x1[off] + g*b2f(Mb[off]);
  }
  __syncthreads();
  int j = threadIdx.x & 63, i0 = (threadIdx.x >> 6)*16;
  #pragma unroll
  for (int r = 0; r < 16; ++r)
    out[((size_t)b*1024 + c0 + i0 + r)*1024 + n0 + j] = t[i0 + r][j];
}

extern "C" void kernel_launch(void* const* d_in, const int* in_sizes, int n_in,
                              void* d_out, int out_size, void* d_ws, size_t ws_size,
                              hipStream_t stream){
  (void)in_sizes; (void)n_in; (void)out_size; (void)ws_size;
  const float* x      = (const float*)d_in[0];
  const float* ln1_w  = (const float*)d_in[1];
  const float* ln1_b  = (const float*)d_in[2];
  const float* Wattn  = (const float*)d_in[3];
  const float* Wproj  = (const float*)d_in[4];
  const float* temp   = (const float*)d_in[5];
  const float* dbias  = (const float*)d_in[6];
  const float* ln2_w  = (const float*)d_in[7];
  const float* ln2_b  = (const float*)d_in[8];
  const float* W1     = (const float*)d_in[9];
  const float* b1     = (const float*)d_in[10];
  const float* W2     = (const float*)d_in[11];
  const float* b2     = (const float*)d_in[12];
  const float* g1     = (const float*)d_in[13];
  const float* g2     = (const float*)d_in[14];
  float* out = (float*)d_out;

  size_t off = 0;
  char* wsb = (char*)d_ws;
  auto alloc = [&](size_t bytes)->char*{
    char* p = wsb + off; off += (bytes + 255) & ~(size_t)255; return p;
  };
  bf16*  Y3  = (bf16*)alloc((size_t)16384*1024*2);   // also Y4
  bf16*  Wb  = (bf16*)alloc((size_t)16384*1024*2);   // also Ab (GEMM2 out)
  bf16*  Yb  = (bf16*)alloc((size_t)16384*1024*2);   // also H chunk
  bf16*  Mb  = (bf16*)alloc((size_t)16384*1024*2);
  float* x1  = (float*)alloc((size_t)16384*1024*4);
  bf16*  WAb = (bf16*)alloc((size_t)1024*1024*2);
  bf16*  WPb = (bf16*)alloc((size_t)1024*1024*2);
  bf16*  W1b = (bf16*)alloc((size_t)4096*1024*2);
  bf16*  W2b = (bf16*)alloc((size_t)4096*1024*2);
  float* mu  = (float*)alloc((size_t)16384*4);
  float* rs  = (float*)alloc((size_t)16384*4);
  float* S   = (float*)alloc((size_t)2048*128*4);
  float* tmp = (float*)alloc((size_t)16*8*1024*4);
  float* Pi  = (float*)alloc((size_t)16*8*1024*4);
  float* Pc  = (float*)alloc((size_t)16*8*1024*4);

  dim3 b256(256), b128(128);

  // weights -> bf16
  k_f2b<<<dim3((1024*1024/4 + 255)/256), b256, 0, stream>>>(Wattn, WAb, 1024*1024);
  k_f2b<<<dim3((1024*1024/4 + 255)/256), b256, 0, stream>>>(Wproj, WPb, 1024*1024);
  k_f2b<<<dim3((4096*1024/4 + 255)/256), b256, 0, stream>>>(W1, W1b, 4096*1024);
  k_f2b<<<dim3((4096*1024/4 + 255)/256), b256, 0, stream>>>(W2, W2b, 4096*1024);

  // LN1
  k_ln1_stats<<<dim3(16, 16), b256, 0, stream>>>(x, mu, rs);
  k_ln1_apply<<<dim3(16, 16, 16), b256, 0, stream>>>(x, mu, rs, ln1_w, ln1_b, Y3);

  // c_attn
  k_gemm<0><<<dim3(8, 128), b256, 0, stream>>>(Y3, WAb, Wb, nullptr, 16384, 1024, 1024);

  // TSSA elementwise chain
  k_chunksum<false><<<dim3(2048), b128, 0, stream>>>(Wb, nullptr, S);
  k_stageA<<<dim3(2048), b128, 0, stream>>>(Wb, S, temp, dbias, tmp);
  k_softmax_scan<<<dim3(128), b256, 0, stream>>>(tmp, Pi, Pc);
  k_chunksum<true><<<dim3(2048), b128, 0, stream>>>(Wb, Pi, S);
  k_stageC<<<dim3(2048), b128, 0, stream>>>(Wb, S, Pi, Pc, Yb);

  // c_proj (writes into Wb slab, now free)
  bf16* Ab = Wb;
  k_gemm<0><<<dim3(8, 128), b256, 0, stream>>>(Yb, WPb, Ab, nullptr, 16384, 1024, 1024);

  // residual 1 (x is (B,C,N); x1 is (B,N,C) fp32)
  k_resid1<<<dim3(16, 16, 16), b256, 0, stream>>>(x, Ab, g1, x1);

  // LN2 -> Y4 (reuse Y3 slab)
  k_ln2<<<dim3(16384), b256, 0, stream>>>(x1, ln2_w, ln2_b, Y3);

  // MLP, M-chunked by 4096 rows; H chunk reuses Yb slab
  for (int ch = 0; ch < 4; ++ch){
    const bf16* Achunk = Y3 + (size_t)ch*4096*1024;
    k_gemm<1><<<dim3(32, 32), b256, 0, stream>>>(Achunk, W1b, Yb, b1, 4096, 4096, 1024);
    k_gemm<2><<<dim3(8, 32), b256, 0, stream>>>(Yb, W2b, Mb + (size_t)ch*4096*1024, b2,
                                                4096, 1024, 4096);
  }

  // residual 2 + transpose to (B,C,H,W)
  k_resid2<<<dim3(16, 16, 16), b256, 0, stream>>>(x1, Mb, g2, out);
}

// Round 2
// 929.709 us; speedup vs baseline: 1.0848x; 1.0848x over previous
//
#include <hip/hip_runtime.h>
#include <hip/hip_bf16.h>
#include <math.h>

using bf16 = __hip_bfloat16;
typedef __bf16 bf16x8 __attribute__((ext_vector_type(8)));
typedef float f32x4 __attribute__((ext_vector_type(4)));

#define EPS16F 0.0009765625f

__device__ __forceinline__ float b2f(bf16 v){ return __bfloat162float(v); }
__device__ __forceinline__ bf16  f2b(float f){ return __float2bfloat16(f); }
__device__ __forceinline__ unsigned short f2bu(float f){
  bf16 h = __float2bfloat16(f); return __builtin_bit_cast(unsigned short, h);
}

__device__ __forceinline__ void gload16(const void* g, void* l){
  __builtin_amdgcn_global_load_lds((const __attribute__((address_space(1))) void*)g,
                                   (__attribute__((address_space(3))) void*)l, 16, 0, 0);
}

// ---------------- fp32 -> bf16 convert ----------------
__global__ void k_f2b(const float* __restrict__ in, bf16* __restrict__ out, int n){
  int i = (blockIdx.x*blockDim.x + threadIdx.x)*4;
  if (i + 3 < n){
    float4 v = *(const float4*)(in + i);
    ushort4 pk = make_ushort4(f2bu(v.x), f2bu(v.y), f2bu(v.z), f2bu(v.w));
    *reinterpret_cast<ushort4*>(out + i) = pk;
  } else {
    for (; i < n; ++i) out[i] = f2b(in[i]);
  }
}

// ---------------- LN1 stats phase 1: partial sums per (b, c-chunk, n) ----------------
__global__ void __launch_bounds__(256) k_ln1_part(const float* __restrict__ x,
                                                  float* __restrict__ Ps,
                                                  float* __restrict__ Pq){
  int chunk = blockIdx.x, b = blockIdx.y;   // 64 chunks of 16 c
  int t = threadIdx.x;                       // 256 threads, each owns 4 n via float4
  const float4* xp = (const float4*)(x + ((size_t)b*1024 + chunk*16)*1024) + t;
  float4 s = {0.f,0.f,0.f,0.f}, q = {0.f,0.f,0.f,0.f};
  #pragma unroll
  for (int c = 0; c < 16; ++c){
    float4 v = xp[c*256];
    s.x += v.x; s.y += v.y; s.z += v.z; s.w += v.w;
    q.x += v.x*v.x; q.y += v.y*v.y; q.z += v.z*v.z; q.w += v.w*v.w;
  }
  size_t o = ((size_t)(b*64 + chunk))*256 + t;
  ((float4*)Ps)[o] = s;
  ((float4*)Pq)[o] = q;
}

// ---------------- LN1 stats phase 2: reduce 64 chunks -> mu, rs ----------------
__global__ void __launch_bounds__(256) k_ln1_finish(const float* __restrict__ Ps,
                                                    const float* __restrict__ Pq,
                                                    float* __restrict__ mu,
                                                    float* __restrict__ rs){
  int nb = blockIdx.x, b = blockIdx.y;
  int n = nb*256 + threadIdx.x;
  const float* ps = Ps + (size_t)b*64*1024 + n;
  const float* pq = Pq + (size_t)b*64*1024 + n;
  float S = 0.f, Q = 0.f;
  #pragma unroll 8
  for (int c = 0; c < 64; ++c){ S += ps[(size_t)c*1024]; Q += pq[(size_t)c*1024]; }
  float m = S*(1.f/1024.f);
  float var = Q*(1.f/1024.f) - m*m;
  mu[b*1024 + n] = m;
  rs[b*1024 + n] = rsqrtf(var + 1e-5f);
}

// ---------------- LN1 apply + transpose: -> Y3 (B,N,C) bf16 ----------------
__global__ void k_ln1_apply(const float* __restrict__ x, const float* __restrict__ mu,
                            const float* __restrict__ rs, const float* __restrict__ w,
                            const float* __restrict__ bias, bf16* __restrict__ y3){
  int b = blockIdx.z, c0 = blockIdx.y*64, n0 = blockIdx.x*64;
  __shared__ float t[64][65];   // [n_local][c_local]
  int j = threadIdx.x & 63, i0 = (threadIdx.x >> 6)*16;
  const float* xp = x + ((size_t)b*1024 + c0)*1024 + n0;
  #pragma unroll
  for (int r = 0; r < 16; ++r)
    t[j][i0 + r] = xp[(size_t)(i0 + r)*1024 + j];
  __syncthreads();
  int i = threadIdx.x & 63, jj0 = (threadIdx.x >> 6)*16;
  float wc = w[c0 + i], bc = bias[c0 + i];
  bf16* yp = y3 + ((size_t)b*1024 + n0)*1024 + c0 + i;
  #pragma unroll
  for (int r = 0; r < 16; ++r){
    int n = n0 + jj0 + r;
    float v = t[jj0 + r][i];
    yp[(size_t)(jj0 + r)*1024] = f2b((v - mu[b*1024 + n])*rs[b*1024 + n]*wc + bc);
  }
}

// ---------------- GEMM: out(M,N) = A(M,K) * W(N,K)^T, bf16 in/out ----------------
// 1D grid with XCD-aware swizzle (grid count always % 8 == 0 here).
// EPI: 0 = plain, 1 = +bias +exact gelu, 2 = +bias
template<int EPI>
__global__ void __launch_bounds__(256) k_gemm(const bf16* __restrict__ A,
                                              const bf16* __restrict__ W,
                                              bf16* __restrict__ out,
                                              const float* __restrict__ bias,
                                              int M, int N, int K, int nbx){
  __shared__ alignas(16) bf16 As[128*64];
  __shared__ alignas(16) bf16 Bs[128*64];
  int nwg = gridDim.x;
  int cpx = nwg >> 3;
  int bid = blockIdx.x;
  int swz = (bid & 7)*cpx + (bid >> 3);
  int bx = swz % nbx, by = swz / nbx;
  int m0 = by*128, n0 = bx*128;
  int t = threadIdx.x;
  int lane = t & 63, wave = t >> 6;
  int wr = wave >> 1, wc = wave & 1;      // 2x2 waves, each owns 64x64
  f32x4 acc[4][4] = {};
  int lr = lane & 15;
  int lg = lane >> 4;

  for (int k0 = 0; k0 < K; k0 += 64){
    #pragma unroll
    for (int i = 0; i < 4; ++i){
      int q = i*256 + t;
      int row = q >> 3, cq = q & 7;
      gload16(A + (size_t)(m0 + row)*K + k0 + cq*8, As + q*8);
      gload16(W + (size_t)(n0 + row)*K + k0 + cq*8, Bs + q*8);
    }
    __syncthreads();
    #pragma unroll
    for (int kk = 0; kk < 2; ++kk){
      int lk = lg*8 + kk*32;
      bf16x8 av[4], bv[4];
      #pragma unroll
      for (int m = 0; m < 4; ++m)
        av[m] = *reinterpret_cast<const bf16x8*>(As + (wr*64 + m*16 + lr)*64 + lk);
      #pragma unroll
      for (int n = 0; n < 4; ++n)
        bv[n] = *reinterpret_cast<const bf16x8*>(Bs + (wc*64 + n*16 + lr)*64 + lk);
      #pragma unroll
      for (int m = 0; m < 4; ++m)
        #pragma unroll
        for (int n = 0; n < 4; ++n)
          acc[m][n] = __builtin_amdgcn_mfma_f32_16x16x32_bf16(av[m], bv[n], acc[m][n], 0, 0, 0);
    }
    __syncthreads();
  }

  #pragma unroll
  for (int m = 0; m < 4; ++m){
    #pragma unroll
    for (int n = 0; n < 4; ++n){
      int col = n0 + wc*64 + n*16 + lr;
      #pragma unroll
      for (int j = 0; j < 4; ++j){
        int row = m0 + wr*64 + m*16 + lg*4 + j;
        float v = acc[m][n][j];
        if (EPI >= 1) v += bias[col];
        if (EPI == 1) v = 0.5f*v*(1.0f + erff(v*0.70710678118654752f));
        out[(size_t)row*N + col] = f2b(v);
      }
    }
  }
}

// ---------------- chunk partial sums of w^2 (optionally * Pi) ----------------
template<bool WEIGHTED>
__global__ void k_chunksum(const bf16* __restrict__ Wb, const float* __restrict__ Pi,
                           float* __restrict__ S){
  int blk = blockIdx.x;
  int ch = blk & 15, h = (blk >> 4) & 7, b = blk >> 7;
  int dd = threadIdx.x;
  const bf16* wp = Wb + ((size_t)(b*1024) + ch*64)*1024 + h*128 + dd;
  float acc = 0.f;
  #pragma unroll 8
  for (int i = 0; i < 64; ++i){
    float w = b2f(wp[(size_t)i*1024]);
    float sq = w*w;
    if (WEIGHTED) sq *= Pi[(size_t)(b*8 + h)*1024 + ch*64 + i];
    acc += sq;
  }
  S[(size_t)blk*128 + dd] = acc;
}

// ---------------- stage A: running denom -> tmp(b,h,n) ----------------
__global__ void k_stageA(const bf16* __restrict__ Wb, const float* __restrict__ S1,
                         const float* __restrict__ temp, const float* __restrict__ dbias,
                         float* __restrict__ tmp){
  int blk = blockIdx.x;
  int ch = blk & 15, h = (blk >> 4) & 7, b = blk >> 7;
  int dd = threadIdx.x;
  const float* sp = S1 + (size_t)(b*8 + h)*16*128 + dd;
  float base = 0.f;
  for (int c = 0; c < ch; ++c) base += sp[(size_t)c*128];
  __shared__ float V[64][129];
  const bf16* wp = Wb + ((size_t)(b*1024) + ch*64)*1024 + h*128 + dd;
  float run = base;
  for (int i = 0; i < 64; ++i){
    float w = b2f(wp[(size_t)i*1024]);
    float sq = w*w;
    run += sq;
    V[i][dd] = sq / fmaxf(run, EPS16F);
  }
  __syncthreads();
  int tt = threadIdx.x;
  int n_loc = tt >> 1, half = tt & 1;
  float s = 0.f;
  for (int k = 0; k < 64; ++k) s += V[n_loc][half*64 + k];
  s += __shfl_xor(s, 1);
  if (half == 0){
    int n = ch*64 + n_loc;
    float db = dbias[h*1024 + n];
    tmp[(size_t)(b*8 + h)*1024 + n] = (s + 128.f*db)*temp[h];
  }
}

// ---------------- softmax over heads + inclusive scan of Pi over n ----------------
__global__ void k_softmax_scan(const float* __restrict__ tmp, float* __restrict__ Pi,
                               float* __restrict__ Pc){
  int bh = blockIdx.x; int b = bh >> 3, h = bh & 7;
  int t = threadIdx.x;
  const float* tp = tmp + (size_t)b*8*1024;
  float p[4];
  #pragma unroll
  for (int i = 0; i < 4; ++i){
    int n = t*4 + i;
    float v[8]; float mx = -1e30f;
    #pragma unroll
    for (int hh = 0; hh < 8; ++hh){ v[hh] = tp[hh*1024 + n]; mx = fmaxf(mx, v[hh]); }
    float Z = 0.f;
    #pragma unroll
    for (int hh = 0; hh < 8; ++hh) Z += expf(v[hh] - mx);
    p[i] = expf(v[h] - mx)/Z;
    Pi[(size_t)bh*1024 + n] = p[i];
  }
  float l0 = p[0], l1 = l0 + p[1], l2 = l1 + p[2], l3 = l2 + p[3];
  float ts = l3, sc = ts;
  int ln = t & 63, wv = t >> 6;
  #pragma unroll
  for (int d = 1; d < 64; d <<= 1){
    float o = __shfl_up(sc, d);
    if (ln >= d) sc += o;
  }
  __shared__ float wsum[4];
  if (ln == 63) wsum[wv] = sc;
  __syncthreads();
  float woff = 0.f;
  for (int w2 = 0; w2 < 4; ++w2) if (w2 < wv) woff += wsum[w2];
  float excl = woff + sc - ts;
  size_t o4 = (size_t)bh*1024 + t*4;
  Pc[o4]   = excl + l0;
  Pc[o4+1] = excl + l1;
  Pc[o4+2] = excl + l2;
  Pc[o4+3] = excl + l3;
}

// ---------------- stage C: dots -> y (B,N,O) bf16 ----------------
__global__ void k_stageC(const bf16* __restrict__ Wb, const float* __restrict__ S2,
                         const float* __restrict__ Pi, const float* __restrict__ Pc,
                         bf16* __restrict__ Y){
  int blk = blockIdx.x;
  int ch = blk & 15, h = (blk >> 4) & 7, b = blk >> 7;
  int dd = threadIdx.x;
  const float* sp = S2 + (size_t)(b*8 + h)*16*128 + dd;
  float base = 0.f;
  for (int c = 0; c < ch; ++c) base += sp[(size_t)c*128];
  const bf16* wp = Wb + ((size_t)(b*1024) + ch*64)*1024 + h*128 + dd;
  bf16* yp = Y + ((size_t)(b*1024) + ch*64)*1024 + h*128 + dd;
  const float* pip = Pi + (size_t)(b*8 + h)*1024 + ch*64;
  const float* pcp = Pc + (size_t)(b*8 + h)*1024 + ch*64;
  float run = base;
  for (int i = 0; i < 64; ++i){
    float w = b2f(wp[(size_t)i*1024]);
    float sq = w*w;
    float pi = pip[i];
    run += sq*pi;
    float dots = run / (pcp[i] + EPS16F);
    float at = 1.0f/(1.0f + dots);
    yp[(size_t)i*1024] = f2b(-(w*pi)*at);
  }
}

// ---------------- residual 1: x1(B,N,C) = xT + g1 * a ----------------
__global__ void k_resid1(const float* __restrict__ x, const bf16* __restrict__ Ab,
                         const float* __restrict__ g1, float* __restrict__ x1){
  int b = blockIdx.z, c0 = blockIdx.y*64, n0 = blockIdx.x*64;
  __shared__ float t[64][65];   // [n_local][c_local]
  int j = threadIdx.x & 63, i0 = (threadIdx.x >> 6)*16;
  const float* xp = x + ((size_t)b*1024 + c0)*1024 + n0;
  #pragma unroll
  for (int r = 0; r < 16; ++r)
    t[j][i0 + r] = xp[(size_t)(i0 + r)*1024 + j];
  __syncthreads();
  int i = threadIdx.x & 63, jj0 = (threadIdx.x >> 6)*16;
  float g = g1[c0 + i];
  #pragma unroll
  for (int r = 0; r < 16; ++r){
    size_t off = ((size_t)b*1024 + n0 + jj0 + r)*1024 + c0 + i;
    x1[off] = t[jj0 + r][i] + g*b2f(Ab[off]);
  }
}

// ---------------- LN2 fused (row-contig) -> Y4 bf16 ----------------
__global__ void k_ln2(const float* __restrict__ x1, const float* __restrict__ w,
                      const float* __restrict__ bias, bf16* __restrict__ y4){
  int row = blockIdx.x, t = threadIdx.x;
  const float4* rp = (const float4*)(x1 + (size_t)row*1024);
  float4 v = rp[t];
  float s = v.x + v.y + v.z + v.w;
  float q = v.x*v.x + v.y*v.y + v.z*v.z + v.w*v.w;
  #pragma unroll
  for (int d = 32; d >= 1; d >>= 1){ s += __shfl_xor(s, d); q += __shfl_xor(q, d); }
  __shared__ float ss[4], qq[4];
  int wv = t >> 6, ln = t & 63;
  if (ln == 0){ ss[wv] = s; qq[wv] = q; }
  __syncthreads();
  s = ss[0] + ss[1] + ss[2] + ss[3];
  q = qq[0] + qq[1] + qq[2] + qq[3];
  float m = s*(1.f/1024.f);
  float var = q*(1.f/1024.f) - m*m;
  float r = rsqrtf(var + 1e-5f);
  int c = t*4;
  ushort4 pk = make_ushort4(
      f2bu((v.x - m)*r*w[c]   + bias[c]),
      f2bu((v.y - m)*r*w[c+1] + bias[c+1]),
      f2bu((v.z - m)*r*w[c+2] + bias[c+2]),
      f2bu((v.w - m)*r*w[c+3] + bias[c+3]));
  *reinterpret_cast<ushort4*>(y4 + (size_t)row*1024 + c) = pk;
}

// ---------------- residual 2 + transpose: out(B,C,N) = x1 + g2*m ----------------
__global__ void k_resid2(const float* __restrict__ x1, const bf16* __restrict__ Mb,
                         const float* __restrict__ g2, float* __restrict__ out){
  int b = blockIdx.z, c0 = blockIdx.y*64, n0 = blockIdx.x*64;
  __shared__ float t[64][65];   // [c_local][n_local]
  int i = threadIdx.x & 63, j0 = (threadIdx.x >> 6)*16;
  float g = g2[c0 + i];
  #pragma unroll
  for (int r = 0; r < 16; ++r){
    size_t off = ((size_t)b*1024 + n0 + j0 + r)*1024 + c0 + i;
    t[i][j0 + r] = x1[off] + g*b2f(Mb[off]);
  }
  __syncthreads();
  int j = threadIdx.x & 63, i0 = (threadIdx.x >> 6)*16;
  #pragma unroll
  for (int r = 0; r < 16; ++r)
    out[((size_t)b*1024 + c0 + i0 + r)*1024 + n0 + j] = t[i0 + r][j];
}

extern "C" void kernel_launch(void* const* d_in, const int* in_sizes, int n_in,
                              void* d_out, int out_size, void* d_ws, size_t ws_size,
                              hipStream_t stream){
  (void)in_sizes; (void)n_in; (void)out_size; (void)ws_size;
  const float* x      = (const float*)d_in[0];
  const float* ln1_w  = (const float*)d_in[1];
  const float* ln1_b  = (const float*)d_in[2];
  const float* Wattn  = (const float*)d_in[3];
  const float* Wproj  = (const float*)d_in[4];
  const float* temp   = (const float*)d_in[5];
  const float* dbias  = (const float*)d_in[6];
  const float* ln2_w  = (const float*)d_in[7];
  const float* ln2_b  = (const float*)d_in[8];
  const float* W1     = (const float*)d_in[9];
  const float* b1     = (const float*)d_in[10];
  const float* W2     = (const float*)d_in[11];
  const float* b2     = (const float*)d_in[12];
  const float* g1     = (const float*)d_in[13];
  const float* g2     = (const float*)d_in[14];
  float* out = (float*)d_out;

  size_t off = 0;
  char* wsb = (char*)d_ws;
  auto alloc = [&](size_t bytes)->char*{
    char* p = wsb + off; off += (bytes + 255) & ~(size_t)255; return p;
  };
  bf16*  Y3  = (bf16*)alloc((size_t)16384*1024*2);   // also Y4
  bf16*  Wb  = (bf16*)alloc((size_t)16384*1024*2);   // also Ab (GEMM2 out)
  bf16*  Yb  = (bf16*)alloc((size_t)16384*1024*2);   // also H chunk
  bf16*  Mb  = (bf16*)alloc((size_t)16384*1024*2);
  float* x1  = (float*)alloc((size_t)16384*1024*4);
  bf16*  WAb = (bf16*)alloc((size_t)1024*1024*2);
  bf16*  WPb = (bf16*)alloc((size_t)1024*1024*2);
  bf16*  W1b = (bf16*)alloc((size_t)4096*1024*2);
  bf16*  W2b = (bf16*)alloc((size_t)4096*1024*2);
  float* mu  = (float*)alloc((size_t)16384*4);
  float* rs  = (float*)alloc((size_t)16384*4);
  float* S   = (float*)alloc((size_t)2048*128*4);
  float* tmp = (float*)alloc((size_t)16*8*1024*4);
  float* Pi  = (float*)alloc((size_t)16*8*1024*4);
  float* Pc  = (float*)alloc((size_t)16*8*1024*4);
  float* Ps  = (float*)alloc((size_t)16*64*1024*4);
  float* Pq  = (float*)alloc((size_t)16*64*1024*4);

  dim3 b256(256), b128(128);

  // weights -> bf16
  k_f2b<<<dim3((1024*1024/4 + 255)/256), b256, 0, stream>>>(Wattn, WAb, 1024*1024);
  k_f2b<<<dim3((1024*1024/4 + 255)/256), b256, 0, stream>>>(Wproj, WPb, 1024*1024);
  k_f2b<<<dim3((4096*1024/4 + 255)/256), b256, 0, stream>>>(W1, W1b, 4096*1024);
  k_f2b<<<dim3((4096*1024/4 + 255)/256), b256, 0, stream>>>(W2, W2b, 4096*1024);

  // LN1 stats (two-phase, coalesced)
  k_ln1_part<<<dim3(64, 16), b256, 0, stream>>>(x, Ps, Pq);
  k_ln1_finish<<<dim3(4, 16), b256, 0, stream>>>(Ps, Pq, mu, rs);
  k_ln1_apply<<<dim3(16, 16, 16), b256, 0, stream>>>(x, mu, rs, ln1_w, ln1_b, Y3);

  // c_attn
  k_gemm<0><<<dim3(8*128), b256, 0, stream>>>(Y3, WAb, Wb, nullptr, 16384, 1024, 1024, 8);

  // TSSA elementwise chain
  k_chunksum<false><<<dim3(2048), b128, 0, stream>>>(Wb, nullptr, S);
  k_stageA<<<dim3(2048), b128, 0, stream>>>(Wb, S, temp, dbias, tmp);
  k_softmax_scan<<<dim3(128), b256, 0, stream>>>(tmp, Pi, Pc);
  k_chunksum<true><<<dim3(2048), b128, 0, stream>>>(Wb, Pi, S);
  k_stageC<<<dim3(2048), b128, 0, stream>>>(Wb, S, Pi, Pc, Yb);

  // c_proj (writes into Wb slab, now free)
  bf16* Ab = Wb;
  k_gemm<0><<<dim3(8*128), b256, 0, stream>>>(Yb, WPb, Ab, nullptr, 16384, 1024, 1024, 8);

  // residual 1 (x is (B,C,N); x1 is (B,N,C) fp32)
  k_resid1<<<dim3(16, 16, 16), b256, 0, stream>>>(x, Ab, g1, x1);

  // LN2 -> Y4 (reuse Y3 slab)
  k_ln2<<<dim3(16384), b256, 0, stream>>>(x1, ln2_w, ln2_b, Y3);

  // MLP, M-chunked by 4096 rows; H chunk reuses Yb slab
  for (int ch = 0; ch < 4; ++ch){
    const bf16* Achunk = Y3 + (size_t)ch*4096*1024;
    k_gemm<1><<<dim3(32*32), b256, 0, stream>>>(Achunk, W1b, Yb, b1, 4096, 4096, 1024, 32);
    k_gemm<2><<<dim3(8*32), b256, 0, stream>>>(Yb, W2b, Mb + (size_t)ch*4096*1024, b2,
                                               4096, 1024, 4096, 8);
  }

  // residual 2 + transpose to (B,C,H,W)
  k_resid2<<<dim3(16, 16, 16), b256, 0, stream>>>(x1, Mb, g2, out);
}

// Round 3
// 842.381 us; speedup vs baseline: 1.1972x; 1.1037x over previous
//
#include <hip/hip_runtime.h>
#include <hip/hip_bf16.h>
#include <math.h>

using bf16 = __hip_bfloat16;
typedef __bf16 bf16x8 __attribute__((ext_vector_type(8)));
typedef float f32x4 __attribute__((ext_vector_type(4)));

#define EPS16F 0.0009765625f

__device__ __forceinline__ float b2f(bf16 v){ return __bfloat162float(v); }
__device__ __forceinline__ bf16  f2b(float f){ return __float2bfloat16(f); }
__device__ __forceinline__ unsigned short f2bu(float f){
  bf16 h = __float2bfloat16(f); return __builtin_bit_cast(unsigned short, h);
}

__device__ __forceinline__ void gload16(const void* g, void* l){
  __builtin_amdgcn_global_load_lds((const __attribute__((address_space(1))) void*)g,
                                   (__attribute__((address_space(3))) void*)l, 16, 0, 0);
}

// ---------------- fp32 -> bf16 convert ----------------
__global__ void k_f2b(const float* __restrict__ in, bf16* __restrict__ out, int n){
  int i = (blockIdx.x*blockDim.x + threadIdx.x)*4;
  if (i + 3 < n){
    float4 v = *(const float4*)(in + i);
    ushort4 pk = make_ushort4(f2bu(v.x), f2bu(v.y), f2bu(v.z), f2bu(v.w));
    *reinterpret_cast<ushort4*>(out + i) = pk;
  } else {
    for (; i < n; ++i) out[i] = f2b(in[i]);
  }
}

// ---------------- LN1 stats phase 1: partial sums per (b, c-chunk, n) ----------------
__global__ void __launch_bounds__(256) k_ln1_part(const float* __restrict__ x,
                                                  float* __restrict__ Ps,
                                                  float* __restrict__ Pq){
  int chunk = blockIdx.x, b = blockIdx.y;   // 64 chunks of 16 c
  int t = threadIdx.x;                       // 256 threads, each owns 4 n via float4
  const float4* xp = (const float4*)(x + ((size_t)b*1024 + chunk*16)*1024) + t;
  float4 s = {0.f,0.f,0.f,0.f}, q = {0.f,0.f,0.f,0.f};
  #pragma unroll
  for (int c = 0; c < 16; ++c){
    float4 v = xp[c*256];
    s.x += v.x; s.y += v.y; s.z += v.z; s.w += v.w;
    q.x += v.x*v.x; q.y += v.y*v.y; q.z += v.z*v.z; q.w += v.w*v.w;
  }
  size_t o = ((size_t)(b*64 + chunk))*256 + t;
  ((float4*)Ps)[o] = s;
  ((float4*)Pq)[o] = q;
}

// ---------------- LN1 stats phase 2: reduce 64 chunks -> mu, rs ----------------
__global__ void __launch_bounds__(256) k_ln1_finish(const float* __restrict__ Ps,
                                                    const float* __restrict__ Pq,
                                                    float* __restrict__ mu,
                                                    float* __restrict__ rs){
  int nb = blockIdx.x, b = blockIdx.y;
  int n = nb*256 + threadIdx.x;
  const float* ps = Ps + (size_t)b*64*1024 + n;
  const float* pq = Pq + (size_t)b*64*1024 + n;
  float S = 0.f, Q = 0.f;
  #pragma unroll 8
  for (int c = 0; c < 64; ++c){ S += ps[(size_t)c*1024]; Q += pq[(size_t)c*1024]; }
  float m = S*(1.f/1024.f);
  float var = Q*(1.f/1024.f) - m*m;
  mu[b*1024 + n] = m;
  rs[b*1024 + n] = rsqrtf(var + 1e-5f);
}

// ---------------- LN1 apply + transpose: -> Y3 (B,N,C) bf16 ----------------
__global__ void k_ln1_apply(const float* __restrict__ x, const float* __restrict__ mu,
                            const float* __restrict__ rs, const float* __restrict__ w,
                            const float* __restrict__ bias, bf16* __restrict__ y3){
  int b = blockIdx.z, c0 = blockIdx.y*64, n0 = blockIdx.x*64;
  __shared__ float t[64][65];   // [n_local][c_local]
  int j = threadIdx.x & 63, i0 = (threadIdx.x >> 6)*16;
  const float* xp = x + ((size_t)b*1024 + c0)*1024 + n0;
  #pragma unroll
  for (int r = 0; r < 16; ++r)
    t[j][i0 + r] = xp[(size_t)(i0 + r)*1024 + j];
  __syncthreads();
  int i = threadIdx.x & 63, jj0 = (threadIdx.x >> 6)*16;
  float wc = w[c0 + i], bc = bias[c0 + i];
  bf16* yp = y3 + ((size_t)b*1024 + n0)*1024 + c0 + i;
  #pragma unroll
  for (int r = 0; r < 16; ++r){
    int n = n0 + jj0 + r;
    float v = t[jj0 + r][i];
    yp[(size_t)(jj0 + r)*1024] = f2b((v - mu[b*1024 + n])*rs[b*1024 + n]*wc + bc);
  }
}

// ---------------- GEMM: out(M,N) = A(M,K) * W(N,K)^T, bf16 in/out ----------------
// 1D grid with XCD-aware swizzle (grid count always % 8 == 0 here).
// LDS chunk-XOR swizzle (both sides): LDS stays linear for global_load_lds;
// the global SOURCE is pre-permuted (chunk ^= row&7) and ds_read applies the
// same XOR. Spreads frag-column reads over all 32 banks (b128 floor).
// EPI: 0 = plain, 1 = +bias +exact gelu, 2 = +bias
template<int EPI>
__global__ void __launch_bounds__(256) k_gemm(const bf16* __restrict__ A,
                                              const bf16* __restrict__ W,
                                              bf16* __restrict__ out,
                                              const float* __restrict__ bias,
                                              int M, int N, int K, int nbx){
  __shared__ alignas(16) bf16 As[128*64];
  __shared__ alignas(16) bf16 Bs[128*64];
  int nwg = gridDim.x;
  int cpx = nwg >> 3;
  int bid = blockIdx.x;
  int swz = (bid & 7)*cpx + (bid >> 3);
  int bx = swz % nbx, by = swz / nbx;
  int m0 = by*128, n0 = bx*128;
  int t = threadIdx.x;
  int lane = t & 63, wave = t >> 6;
  int wr = wave >> 1, wc = wave & 1;      // 2x2 waves, each owns 64x64
  f32x4 acc[4][4] = {};
  int lr = lane & 15;
  int lg = lane >> 4;
  int rx = lr & 7;                         // read-side swizzle key

  for (int k0 = 0; k0 < K; k0 += 64){
    #pragma unroll
    for (int i = 0; i < 4; ++i){
      int q = i*256 + t;
      int row = q >> 3, cq = q & 7;
      int cs = cq ^ (row & 7);             // pre-swizzled global source chunk
      gload16(A + (size_t)(m0 + row)*K + k0 + cs*8, As + q*8);
      gload16(W + (size_t)(n0 + row)*K + k0 + cs*8, Bs + q*8);
    }
    __syncthreads();
    #pragma unroll
    for (int kk = 0; kk < 2; ++kk){
      int ck = (lg + kk*4);
      int lk = (ck ^ rx)*8;                // swizzled chunk on read
      bf16x8 av[4], bv[4];
      #pragma unroll
      for (int m = 0; m < 4; ++m)
        av[m] = *reinterpret_cast<const bf16x8*>(As + (wr*64 + m*16 + lr)*64 + lk);
      #pragma unroll
      for (int n = 0; n < 4; ++n)
        bv[n] = *reinterpret_cast<const bf16x8*>(Bs + (wc*64 + n*16 + lr)*64 + lk);
      #pragma unroll
      for (int m = 0; m < 4; ++m)
        #pragma unroll
        for (int n = 0; n < 4; ++n)
          acc[m][n] = __builtin_amdgcn_mfma_f32_16x16x32_bf16(av[m], bv[n], acc[m][n], 0, 0, 0);
    }
    __syncthreads();
  }

  #pragma unroll
  for (int m = 0; m < 4; ++m){
    #pragma unroll
    for (int n = 0; n < 4; ++n){
      int col = n0 + wc*64 + n*16 + lr;
      #pragma unroll
      for (int j = 0; j < 4; ++j){
        int row = m0 + wr*64 + m*16 + lg*4 + j;
        float v = acc[m][n][j];
        if (EPI >= 1) v += bias[col];
        if (EPI == 1) v = 0.5f*v*(1.0f + erff(v*0.70710678118654752f));
        out[(size_t)row*N + col] = f2b(v);
      }
    }
  }
}

// ---------------- chunk partial sums of w^2 (optionally * Pi) ----------------
template<bool WEIGHTED>
__global__ void k_chunksum(const bf16* __restrict__ Wb, const float* __restrict__ Pi,
                           float* __restrict__ S){
  int blk = blockIdx.x;
  int ch = blk & 15, h = (blk >> 4) & 7, b = blk >> 7;
  int dd = threadIdx.x;
  const bf16* wp = Wb + ((size_t)(b*1024) + ch*64)*1024 + h*128 + dd;
  float acc = 0.f;
  #pragma unroll 8
  for (int i = 0; i < 64; ++i){
    float w = b2f(wp[(size_t)i*1024]);
    float sq = w*w;
    if (WEIGHTED) sq *= Pi[(size_t)(b*8 + h)*1024 + ch*64 + i];
    acc += sq;
  }
  S[(size_t)blk*128 + dd] = acc;
}

// ---------------- stage A: running denom -> tmp(b,h,n) ----------------
__global__ void k_stageA(const bf16* __restrict__ Wb, const float* __restrict__ S1,
                         const float* __restrict__ temp, const float* __restrict__ dbias,
                         float* __restrict__ tmp){
  int blk = blockIdx.x;
  int ch = blk & 15, h = (blk >> 4) & 7, b = blk >> 7;
  int dd = threadIdx.x;
  const float* sp = S1 + (size_t)(b*8 + h)*16*128 + dd;
  float base = 0.f;
  for (int c = 0; c < ch; ++c) base += sp[(size_t)c*128];
  __shared__ float V[64][129];
  const bf16* wp = Wb + ((size_t)(b*1024) + ch*64)*1024 + h*128 + dd;
  float run = base;
  for (int i = 0; i < 64; ++i){
    float w = b2f(wp[(size_t)i*1024]);
    float sq = w*w;
    run += sq;
    V[i][dd] = sq / fmaxf(run, EPS16F);
  }
  __syncthreads();
  int tt = threadIdx.x;
  int n_loc = tt >> 1, half = tt & 1;
  float s = 0.f;
  for (int k = 0; k < 64; ++k) s += V[n_loc][half*64 + k];
  s += __shfl_xor(s, 1);
  if (half == 0){
    int n = ch*64 + n_loc;
    float db = dbias[h*1024 + n];
    tmp[(size_t)(b*8 + h)*1024 + n] = (s + 128.f*db)*temp[h];
  }
}

// ---------------- softmax over heads + inclusive scan of Pi over n ----------------
__global__ void k_softmax_scan(const float* __restrict__ tmp, float* __restrict__ Pi,
                               float* __restrict__ Pc){
  int bh = blockIdx.x; int b = bh >> 3, h = bh & 7;
  int t = threadIdx.x;
  const float* tp = tmp + (size_t)b*8*1024;
  float p[4];
  #pragma unroll
  for (int i = 0; i < 4; ++i){
    int n = t*4 + i;
    float v[8]; float mx = -1e30f;
    #pragma unroll
    for (int hh = 0; hh < 8; ++hh){ v[hh] = tp[hh*1024 + n]; mx = fmaxf(mx, v[hh]); }
    float Z = 0.f;
    #pragma unroll
    for (int hh = 0; hh < 8; ++hh) Z += expf(v[hh] - mx);
    p[i] = expf(v[h] - mx)/Z;
    Pi[(size_t)bh*1024 + n] = p[i];
  }
  float l0 = p[0], l1 = l0 + p[1], l2 = l1 + p[2], l3 = l2 + p[3];
  float ts = l3, sc = ts;
  int ln = t & 63, wv = t >> 6;
  #pragma unroll
  for (int d = 1; d < 64; d <<= 1){
    float o = __shfl_up(sc, d);
    if (ln >= d) sc += o;
  }
  __shared__ float wsum[4];
  if (ln == 63) wsum[wv] = sc;
  __syncthreads();
  float woff = 0.f;
  for (int w2 = 0; w2 < 4; ++w2) if (w2 < wv) woff += wsum[w2];
  float excl = woff + sc - ts;
  size_t o4 = (size_t)bh*1024 + t*4;
  Pc[o4]   = excl + l0;
  Pc[o4+1] = excl + l1;
  Pc[o4+2] = excl + l2;
  Pc[o4+3] = excl + l3;
}

// ---------------- stage C: dots -> y (B,N,O) bf16 ----------------
__global__ void k_stageC(const bf16* __restrict__ Wb, const float* __restrict__ S2,
                         const float* __restrict__ Pi, const float* __restrict__ Pc,
                         bf16* __restrict__ Y){
  int blk = blockIdx.x;
  int ch = blk & 15, h = (blk >> 4) & 7, b = blk >> 7;
  int dd = threadIdx.x;
  const float* sp = S2 + (size_t)(b*8 + h)*16*128 + dd;
  float base = 0.f;
  for (int c = 0; c < ch; ++c) base += sp[(size_t)c*128];
  const bf16* wp = Wb + ((size_t)(b*1024) + ch*64)*1024 + h*128 + dd;
  bf16* yp = Y + ((size_t)(b*1024) + ch*64)*1024 + h*128 + dd;
  const float* pip = Pi + (size_t)(b*8 + h)*1024 + ch*64;
  const float* pcp = Pc + (size_t)(b*8 + h)*1024 + ch*64;
  float run = base;
  for (int i = 0; i < 64; ++i){
    float w = b2f(wp[(size_t)i*1024]);
    float sq = w*w;
    float pi = pip[i];
    run += sq*pi;
    float dots = run / (pcp[i] + EPS16F);
    float at = 1.0f/(1.0f + dots);
    yp[(size_t)i*1024] = f2b(-(w*pi)*at);
  }
}

// ---------------- residual 1: x1(B,N,C) = xT + g1 * a ----------------
__global__ void k_resid1(const float* __restrict__ x, const bf16* __restrict__ Ab,
                         const float* __restrict__ g1, float* __restrict__ x1){
  int b = blockIdx.z, c0 = blockIdx.y*64, n0 = blockIdx.x*64;
  __shared__ float t[64][65];   // [n_local][c_local]
  int j = threadIdx.x & 63, i0 = (threadIdx.x >> 6)*16;
  const float* xp = x + ((size_t)b*1024 + c0)*1024 + n0;
  #pragma unroll
  for (int r = 0; r < 16; ++r)
    t[j][i0 + r] = xp[(size_t)(i0 + r)*1024 + j];
  __syncthreads();
  int i = threadIdx.x & 63, jj0 = (threadIdx.x >> 6)*16;
  float g = g1[c0 + i];
  #pragma unroll
  for (int r = 0; r < 16; ++r){
    size_t off = ((size_t)b*1024 + n0 + jj0 + r)*1024 + c0 + i;
    x1[off] = t[jj0 + r][i] + g*b2f(Ab[off]);
  }
}

// ---------------- LN2 fused (row-contig) -> Y4 bf16 ----------------
__global__ void k_ln2(const float* __restrict__ x1, const float* __restrict__ w,
                      const float* __restrict__ bias, bf16* __restrict__ y4){
  int row = blockIdx.x, t = threadIdx.x;
  const float4* rp = (const float4*)(x1 + (size_t)row*1024);
  float4 v = rp[t];
  float s = v.x + v.y + v.z + v.w;
  float q = v.x*v.x + v.y*v.y + v.z*v.z + v.w*v.w;
  #pragma unroll
  for (int d = 32; d >= 1; d >>= 1){ s += __shfl_xor(s, d); q += __shfl_xor(q, d); }
  __shared__ float ss[4], qq[4];
  int wv = t >> 6, ln = t & 63;
  if (ln == 0){ ss[wv] = s; qq[wv] = q; }
  __syncthreads();
  s = ss[0] + ss[1] + ss[2] + ss[3];
  q = qq[0] + qq[1] + qq[2] + qq[3];
  float m = s*(1.f/1024.f);
  float var = q*(1.f/1024.f) - m*m;
  float r = rsqrtf(var + 1e-5f);
  int c = t*4;
  ushort4 pk = make_ushort4(
      f2bu((v.x - m)*r*w[c]   + bias[c]),
      f2bu((v.y - m)*r*w[c+1] + bias[c+1]),
      f2bu((v.z - m)*r*w[c+2] + bias[c+2]),
      f2bu((v.w - m)*r*w[c+3] + bias[c+3]));
  *reinterpret_cast<ushort4*>(y4 + (size_t)row*1024 + c) = pk;
}

// ---------------- residual 2 + transpose: out(B,C,N) = x1 + g2*m ----------------
__global__ void k_resid2(const float* __restrict__ x1, const bf16* __restrict__ Mb,
                         const float* __restrict__ g2, float* __restrict__ out){
  int b = blockIdx.z, c0 = blockIdx.y*64, n0 = blockIdx.x*64;
  __shared__ float t[64][65];   // [c_local][n_local]
  int i = threadIdx.x & 63, j0 = (threadIdx.x >> 6)*16;
  float g = g2[c0 + i];
  #pragma unroll
  for (int r = 0; r < 16; ++r){
    size_t off = ((size_t)b*1024 + n0 + j0 + r)*1024 + c0 + i;
    t[i][j0 + r] = x1[off] + g*b2f(Mb[off]);
  }
  __syncthreads();
  int j = threadIdx.x & 63, i0 = (threadIdx.x >> 6)*16;
  #pragma unroll
  for (int r = 0; r < 16; ++r)
    out[((size_t)b*1024 + c0 + i0 + r)*1024 + n0 + j] = t[i0 + r][j];
}

extern "C" void kernel_launch(void* const* d_in, const int* in_sizes, int n_in,
                              void* d_out, int out_size, void* d_ws, size_t ws_size,
                              hipStream_t stream){
  (void)in_sizes; (void)n_in; (void)out_size;
  const float* x      = (const float*)d_in[0];
  const float* ln1_w  = (const float*)d_in[1];
  const float* ln1_b  = (const float*)d_in[2];
  const float* Wattn  = (const float*)d_in[3];
  const float* Wproj  = (const float*)d_in[4];
  const float* temp   = (const float*)d_in[5];
  const float* dbias  = (const float*)d_in[6];
  const float* ln2_w  = (const float*)d_in[7];
  const float* ln2_b  = (const float*)d_in[8];
  const float* W1     = (const float*)d_in[9];
  const float* b1     = (const float*)d_in[10];
  const float* W2     = (const float*)d_in[11];
  const float* b2     = (const float*)d_in[12];
  const float* g1     = (const float*)d_in[13];
  const float* g2     = (const float*)d_in[14];
  float* out = (float*)d_out;

  size_t off = 0;
  char* wsb = (char*)d_ws;
  auto alloc = [&](size_t bytes)->char*{
    char* p = wsb + off; off += (bytes + 255) & ~(size_t)255; return p;
  };
  bf16*  Y3  = (bf16*)alloc((size_t)16384*1024*2);   // also Y4
  bf16*  Wb  = (bf16*)alloc((size_t)16384*1024*2);   // also Ab (GEMM2 out)
  bf16*  Yb  = (bf16*)alloc((size_t)16384*1024*2);   // TSSA y; H fallback
  bf16*  Mb  = (bf16*)alloc((size_t)16384*1024*2);
  float* x1  = (float*)alloc((size_t)16384*1024*4);
  bf16*  WAb = (bf16*)alloc((size_t)1024*1024*2);
  bf16*  WPb = (bf16*)alloc((size_t)1024*1024*2);
  bf16*  W1b = (bf16*)alloc((size_t)4096*1024*2);
  bf16*  W2b = (bf16*)alloc((size_t)4096*1024*2);
  float* mu  = (float*)alloc((size_t)16384*4);
  float* rs  = (float*)alloc((size_t)16384*4);
  float* S   = (float*)alloc((size_t)2048*128*4);
  float* tmp = (float*)alloc((size_t)16*8*1024*4);
  float* Pi  = (float*)alloc((size_t)16*8*1024*4);
  float* Pc  = (float*)alloc((size_t)16*8*1024*4);
  float* Ps  = (float*)alloc((size_t)16*64*1024*4);
  float* Pq  = (float*)alloc((size_t)16*64*1024*4);

  // MLP hidden buffer: un-chunk if workspace allows (occupancy fix for MLP-down)
  size_t rem = (ws_size > off) ? ws_size - off : 0;
  int nchunk; bf16* Hb;
  if (rem >= (size_t)16384*4096*2 + 256){ nchunk = 1; Hb = (bf16*)alloc((size_t)16384*4096*2); }
  else if (rem >= (size_t)8192*4096*2 + 256){ nchunk = 2; Hb = (bf16*)alloc((size_t)8192*4096*2); }
  else { nchunk = 4; Hb = Yb; }
  int Mc = 16384 / nchunk;

  dim3 b256(256), b128(128);

  // weights -> bf16
  k_f2b<<<dim3((1024*1024/4 + 255)/256), b256, 0, stream>>>(Wattn, WAb, 1024*1024);
  k_f2b<<<dim3((1024*1024/4 + 255)/256), b256, 0, stream>>>(Wproj, WPb, 1024*1024);
  k_f2b<<<dim3((4096*1024/4 + 255)/256), b256, 0, stream>>>(W1, W1b, 4096*1024);
  k_f2b<<<dim3((4096*1024/4 + 255)/256), b256, 0, stream>>>(W2, W2b, 4096*1024);

  // LN1 stats (two-phase, coalesced)
  k_ln1_part<<<dim3(64, 16), b256, 0, stream>>>(x, Ps, Pq);
  k_ln1_finish<<<dim3(4, 16), b256, 0, stream>>>(Ps, Pq, mu, rs);
  k_ln1_apply<<<dim3(16, 16, 16), b256, 0, stream>>>(x, mu, rs, ln1_w, ln1_b, Y3);

  // c_attn
  k_gemm<0><<<dim3(8*128), b256, 0, stream>>>(Y3, WAb, Wb, nullptr, 16384, 1024, 1024, 8);

  // TSSA elementwise chain
  k_chunksum<false><<<dim3(2048), b128, 0, stream>>>(Wb, nullptr, S);
  k_stageA<<<dim3(2048), b128, 0, stream>>>(Wb, S, temp, dbias, tmp);
  k_softmax_scan<<<dim3(128), b256, 0, stream>>>(tmp, Pi, Pc);
  k_chunksum<true><<<dim3(2048), b128, 0, stream>>>(Wb, Pi, S);
  k_stageC<<<dim3(2048), b128, 0, stream>>>(Wb, S, Pi, Pc, Yb);

  // c_proj (writes into Wb slab, now free)
  bf16* Ab = Wb;
  k_gemm<0><<<dim3(8*128), b256, 0, stream>>>(Yb, WPb, Ab, nullptr, 16384, 1024, 1024, 8);

  // residual 1 (x is (B,C,N); x1 is (B,N,C) fp32)
  k_resid1<<<dim3(16, 16, 16), b256, 0, stream>>>(x, Ab, g1, x1);

  // LN2 -> Y4 (reuse Y3 slab)
  k_ln2<<<dim3(16384), b256, 0, stream>>>(x1, ln2_w, ln2_b, Y3);

  // MLP (nchunk=1 when ws allows: full-grid dispatches for occupancy)
  for (int ch = 0; ch < nchunk; ++ch){
    const bf16* Achunk = Y3 + (size_t)ch*Mc*1024;
    k_gemm<1><<<dim3(32*(Mc/128)), b256, 0, stream>>>(Achunk, W1b, Hb, b1, Mc, 4096, 1024, 32);
    k_gemm<2><<<dim3(8*(Mc/128)), b256, 0, stream>>>(Hb, W2b, Mb + (size_t)ch*Mc*1024, b2,
                                                     Mc, 1024, 4096, 8);
  }

  // residual 2 + transpose to (B,C,H,W)
  k_resid2<<<dim3(16, 16, 16), b256, 0, stream>>>(x1, Mb, g2, out);
}

// Round 4
// 706.606 us; speedup vs baseline: 1.4273x; 1.1922x over previous
//
#include <hip/hip_runtime.h>
#include <hip/hip_bf16.h>
#include <math.h>

using bf16 = __hip_bfloat16;
typedef __bf16 bf16x8 __attribute__((ext_vector_type(8)));
typedef float f32x4 __attribute__((ext_vector_type(4)));

#define EPS16F 0.0009765625f

__device__ __forceinline__ float b2f(bf16 v){ return __bfloat162float(v); }
__device__ __forceinline__ bf16  f2b(float f){ return __float2bfloat16(f); }
__device__ __forceinline__ unsigned short f2bu(float f){
  bf16 h = __float2bfloat16(f); return __builtin_bit_cast(unsigned short, h);
}

__device__ __forceinline__ void gload16(const void* g, void* l){
  __builtin_amdgcn_global_load_lds((const __attribute__((address_space(1))) void*)g,
                                   (__attribute__((address_space(3))) void*)l, 16, 0, 0);
}

// ---------------- fp32 -> bf16 convert ----------------
__global__ void k_f2b(const float* __restrict__ in, bf16* __restrict__ out, int n){
  int i = (blockIdx.x*blockDim.x + threadIdx.x)*4;
  if (i + 3 < n){
    float4 v = *(const float4*)(in + i);
    ushort4 pk = make_ushort4(f2bu(v.x), f2bu(v.y), f2bu(v.z), f2bu(v.w));
    *reinterpret_cast<ushort4*>(out + i) = pk;
  } else {
    for (; i < n; ++i) out[i] = f2b(in[i]);
  }
}

// ---------------- LN1 stats phase 1: partial sums per (b, c-chunk, n) ----------------
__global__ void __launch_bounds__(256) k_ln1_part(const float* __restrict__ x,
                                                  float* __restrict__ Ps,
                                                  float* __restrict__ Pq){
  int chunk = blockIdx.x, b = blockIdx.y;   // 64 chunks of 16 c
  int t = threadIdx.x;                       // 256 threads, each owns 4 n via float4
  const float4* xp = (const float4*)(x + ((size_t)b*1024 + chunk*16)*1024) + t;
  float4 s = {0.f,0.f,0.f,0.f}, q = {0.f,0.f,0.f,0.f};
  #pragma unroll
  for (int c = 0; c < 16; ++c){
    float4 v = xp[c*256];
    s.x += v.x; s.y += v.y; s.z += v.z; s.w += v.w;
    q.x += v.x*v.x; q.y += v.y*v.y; q.z += v.z*v.z; q.w += v.w*v.w;
  }
  size_t o = ((size_t)(b*64 + chunk))*256 + t;
  ((float4*)Ps)[o] = s;
  ((float4*)Pq)[o] = q;
}

// ---------------- LN1 stats phase 2: reduce 64 chunks -> mu, rs ----------------
__global__ void __launch_bounds__(256) k_ln1_finish(const float* __restrict__ Ps,
                                                    const float* __restrict__ Pq,
                                                    float* __restrict__ mu,
                                                    float* __restrict__ rs){
  int nb = blockIdx.x, b = blockIdx.y;
  int n = nb*256 + threadIdx.x;
  const float* ps = Ps + (size_t)b*64*1024 + n;
  const float* pq = Pq + (size_t)b*64*1024 + n;
  float S = 0.f, Q = 0.f;
  #pragma unroll 8
  for (int c = 0; c < 64; ++c){ S += ps[(size_t)c*1024]; Q += pq[(size_t)c*1024]; }
  float m = S*(1.f/1024.f);
  float var = Q*(1.f/1024.f) - m*m;
  mu[b*1024 + n] = m;
  rs[b*1024 + n] = rsqrtf(var + 1e-5f);
}

// ---------------- LN1 apply + transpose: -> Y3 (B,N,C) bf16 ----------------
__global__ void k_ln1_apply(const float* __restrict__ x, const float* __restrict__ mu,
                            const float* __restrict__ rs, const float* __restrict__ w,
                            const float* __restrict__ bias, bf16* __restrict__ y3){
  int b = blockIdx.z, c0 = blockIdx.y*64, n0 = blockIdx.x*64;
  __shared__ float t[64][65];   // [n_local][c_local]
  int j = threadIdx.x & 63, i0 = (threadIdx.x >> 6)*16;
  const float* xp = x + ((size_t)b*1024 + c0)*1024 + n0;
  #pragma unroll
  for (int r = 0; r < 16; ++r)
    t[j][i0 + r] = xp[(size_t)(i0 + r)*1024 + j];
  __syncthreads();
  int i = threadIdx.x & 63, jj0 = (threadIdx.x >> 6)*16;
  float wc = w[c0 + i], bc = bias[c0 + i];
  bf16* yp = y3 + ((size_t)b*1024 + n0)*1024 + c0 + i;
  #pragma unroll
  for (int r = 0; r < 16; ++r){
    int n = n0 + jj0 + r;
    float v = t[jj0 + r][i];
    yp[(size_t)(jj0 + r)*1024] = f2b((v - mu[b*1024 + n])*rs[b*1024 + n]*wc + bc);
  }
}

// ---------------- GEMM: out(M,N) = A(M,K) * W(N,K)^T, bf16 in/out ----------------
// Strided (lda/ldw/ldo) so F-sliced weight views work. 1D grid, XCD swizzle.
// LDS chunk-XOR swizzle both-sides (linear LDS dest for global_load_lds;
// pre-swizzled global source chunk; same XOR on ds_read).
// EPI: 0 = plain, 1 = +bias +exact gelu, 2 = +bias, 3 = +bias +accumulate-into-out
template<int EPI>
__global__ void __launch_bounds__(256) k_gemm(const bf16* __restrict__ A,
                                              const bf16* __restrict__ W,
                                              bf16* __restrict__ out,
                                              const float* __restrict__ bias,
                                              int M, int N, int K,
                                              int lda, int ldw, int ldo, int nbx){
  __shared__ alignas(16) bf16 As[128*64];
  __shared__ alignas(16) bf16 Bs[128*64];
  int nwg = gridDim.x;
  int cpx = nwg >> 3;
  int bid = blockIdx.x;
  int swz = (bid & 7)*cpx + (bid >> 3);
  int bx = swz % nbx, by = swz / nbx;
  int m0 = by*128, n0 = bx*128;
  int t = threadIdx.x;
  int lane = t & 63, wave = t >> 6;
  int wr = wave >> 1, wc = wave & 1;      // 2x2 waves, each owns 64x64
  f32x4 acc[4][4] = {};
  int lr = lane & 15;
  int lg = lane >> 4;
  int rx = lr & 7;                         // read-side swizzle key

  for (int k0 = 0; k0 < K; k0 += 64){
    #pragma unroll
    for (int i = 0; i < 4; ++i){
      int q = i*256 + t;
      int row = q >> 3, cq = q & 7;
      int cs = cq ^ (row & 7);             // pre-swizzled global source chunk
      gload16(A + (size_t)(m0 + row)*lda + k0 + cs*8, As + q*8);
      gload16(W + (size_t)(n0 + row)*ldw + k0 + cs*8, Bs + q*8);
    }
    __syncthreads();
    #pragma unroll
    for (int kk = 0; kk < 2; ++kk){
      int ck = (lg + kk*4);
      int lk = (ck ^ rx)*8;                // swizzled chunk on read
      bf16x8 av[4], bv[4];
      #pragma unroll
      for (int m = 0; m < 4; ++m)
        av[m] = *reinterpret_cast<const bf16x8*>(As + (wr*64 + m*16 + lr)*64 + lk);
      #pragma unroll
      for (int n = 0; n < 4; ++n)
        bv[n] = *reinterpret_cast<const bf16x8*>(Bs + (wc*64 + n*16 + lr)*64 + lk);
      #pragma unroll
      for (int m = 0; m < 4; ++m)
        #pragma unroll
        for (int n = 0; n < 4; ++n)
          acc[m][n] = __builtin_amdgcn_mfma_f32_16x16x32_bf16(av[m], bv[n], acc[m][n], 0, 0, 0);
    }
    __syncthreads();
  }

  #pragma unroll
  for (int m = 0; m < 4; ++m){
    #pragma unroll
    for (int n = 0; n < 4; ++n){
      int col = n0 + wc*64 + n*16 + lr;
      #pragma unroll
      for (int j = 0; j < 4; ++j){
        int row = m0 + wr*64 + m*16 + lg*4 + j;
        size_t idx = (size_t)row*ldo + col;
        float v = acc[m][n][j];
        if (EPI >= 1) v += bias[col];
        if (EPI == 1) v = 0.5f*v*(1.0f + erff(v*0.70710678118654752f));
        if (EPI == 3) v += b2f(out[idx]);
        out[idx] = f2b(v);
      }
    }
  }
}

// ---------------- chunk partial sums of w^2 (optionally * Pi) ----------------
template<bool WEIGHTED>
__global__ void k_chunksum(const bf16* __restrict__ Wb, const float* __restrict__ Pi,
                           float* __restrict__ S){
  int blk = blockIdx.x;
  int ch = blk & 15, h = (blk >> 4) & 7, b = blk >> 7;
  int dd = threadIdx.x;
  const bf16* wp = Wb + ((size_t)(b*1024) + ch*64)*1024 + h*128 + dd;
  float acc = 0.f;
  #pragma unroll 8
  for (int i = 0; i < 64; ++i){
    float w = b2f(wp[(size_t)i*1024]);
    float sq = w*w;
    if (WEIGHTED) sq *= Pi[(size_t)(b*8 + h)*1024 + ch*64 + i];
    acc += sq;
  }
  S[(size_t)blk*128 + dd] = acc;
}

// ---------------- stage A: running denom -> tmp(b,h,n) ----------------
__global__ void k_stageA(const bf16* __restrict__ Wb, const float* __restrict__ S1,
                         const float* __restrict__ temp, const float* __restrict__ dbias,
                         float* __restrict__ tmp){
  int blk = blockIdx.x;
  int ch = blk & 15, h = (blk >> 4) & 7, b = blk >> 7;
  int dd = threadIdx.x;
  const float* sp = S1 + (size_t)(b*8 + h)*16*128 + dd;
  float base = 0.f;
  for (int c = 0; c < ch; ++c) base += sp[(size_t)c*128];
  __shared__ float V[64][129];
  const bf16* wp = Wb + ((size_t)(b*1024) + ch*64)*1024 + h*128 + dd;
  float run = base;
  for (int i = 0; i < 64; ++i){
    float w = b2f(wp[(size_t)i*1024]);
    float sq = w*w;
    run += sq;
    V[i][dd] = sq / fmaxf(run, EPS16F);
  }
  __syncthreads();
  int tt = threadIdx.x;
  int n_loc = tt >> 1, half = tt & 1;
  float s = 0.f;
  for (int k = 0; k < 64; ++k) s += V[n_loc][half*64 + k];
  s += __shfl_xor(s, 1);
  if (half == 0){
    int n = ch*64 + n_loc;
    float db = dbias[h*1024 + n];
    tmp[(size_t)(b*8 + h)*1024 + n] = (s + 128.f*db)*temp[h];
  }
}

// ---------------- softmax over heads + inclusive scan of Pi over n ----------------
__global__ void k_softmax_scan(const float* __restrict__ tmp, float* __restrict__ Pi,
                               float* __restrict__ Pc){
  int bh = blockIdx.x; int b = bh >> 3, h = bh & 7;
  int t = threadIdx.x;
  const float* tp = tmp + (size_t)b*8*1024;
  float p[4];
  #pragma unroll
  for (int i = 0; i < 4; ++i){
    int n = t*4 + i;
    float v[8]; float mx = -1e30f;
    #pragma unroll
    for (int hh = 0; hh < 8; ++hh){ v[hh] = tp[hh*1024 + n]; mx = fmaxf(mx, v[hh]); }
    float Z = 0.f;
    #pragma unroll
    for (int hh = 0; hh < 8; ++hh) Z += expf(v[hh] - mx);
    p[i] = expf(v[h] - mx)/Z;
    Pi[(size_t)bh*1024 + n] = p[i];
  }
  float l0 = p[0], l1 = l0 + p[1], l2 = l1 + p[2], l3 = l2 + p[3];
  float ts = l3, sc = ts;
  int ln = t & 63, wv = t >> 6;
  #pragma unroll
  for (int d = 1; d < 64; d <<= 1){
    float o = __shfl_up(sc, d);
    if (ln >= d) sc += o;
  }
  __shared__ float wsum[4];
  if (ln == 63) wsum[wv] = sc;
  __syncthreads();
  float woff = 0.f;
  for (int w2 = 0; w2 < 4; ++w2) if (w2 < wv) woff += wsum[w2];
  float excl = woff + sc - ts;
  size_t o4 = (size_t)bh*1024 + t*4;
  Pc[o4]   = excl + l0;
  Pc[o4+1] = excl + l1;
  Pc[o4+2] = excl + l2;
  Pc[o4+3] = excl + l3;
}

// ---------------- stage C: dots -> y (B,N,O) bf16 ----------------
__global__ void k_stageC(const bf16* __restrict__ Wb, const float* __restrict__ S2,
                         const float* __restrict__ Pi, const float* __restrict__ Pc,
                         bf16* __restrict__ Y){
  int blk = blockIdx.x;
  int ch = blk & 15, h = (blk >> 4) & 7, b = blk >> 7;
  int dd = threadIdx.x;
  const float* sp = S2 + (size_t)(b*8 + h)*16*128 + dd;
  float base = 0.f;
  for (int c = 0; c < ch; ++c) base += sp[(size_t)c*128];
  const bf16* wp = Wb + ((size_t)(b*1024) + ch*64)*1024 + h*128 + dd;
  bf16* yp = Y + ((size_t)(b*1024) + ch*64)*1024 + h*128 + dd;
  const float* pip = Pi + (size_t)(b*8 + h)*1024 + ch*64;
  const float* pcp = Pc + (size_t)(b*8 + h)*1024 + ch*64;
  float run = base;
  for (int i = 0; i < 64; ++i){
    float w = b2f(wp[(size_t)i*1024]);
    float sq = w*w;
    float pi = pip[i];
    run += sq*pi;
    float dots = run / (pcp[i] + EPS16F);
    float at = 1.0f/(1.0f + dots);
    yp[(size_t)i*1024] = f2b(-(w*pi)*at);
  }
}

// ---------------- residual 1: x1(B,N,C) = xT + g1 * a ----------------
__global__ void k_resid1(const float* __restrict__ x, const bf16* __restrict__ Ab,
                         const float* __restrict__ g1, float* __restrict__ x1){
  int b = blockIdx.z, c0 = blockIdx.y*64, n0 = blockIdx.x*64;
  __shared__ float t[64][65];   // [n_local][c_local]
  int j = threadIdx.x & 63, i0 = (threadIdx.x >> 6)*16;
  const float* xp = x + ((size_t)b*1024 + c0)*1024 + n0;
  #pragma unroll
  for (int r = 0; r < 16; ++r)
    t[j][i0 + r] = xp[(size_t)(i0 + r)*1024 + j];
  __syncthreads();
  int i = threadIdx.x & 63, jj0 = (threadIdx.x >> 6)*16;
  float g = g1[c0 + i];
  #pragma unroll
  for (int r = 0; r < 16; ++r){
    size_t off = ((size_t)b*1024 + n0 + jj0 + r)*1024 + c0 + i;
    x1[off] = t[jj0 + r][i] + g*b2f(Ab[off]);
  }
}

// ---------------- LN2 fused (row-contig) -> Y4 bf16 ----------------
__global__ void k_ln2(const float* __restrict__ x1, const float* __restrict__ w,
                      const float* __restrict__ bias, bf16* __restrict__ y4){
  int row = blockIdx.x, t = threadIdx.x;
  const float4* rp = (const float4*)(x1 + (size_t)row*1024);
  float4 v = rp[t];
  float s = v.x + v.y + v.z + v.w;
  float q = v.x*v.x + v.y*v.y + v.z*v.z + v.w*v.w;
  #pragma unroll
  for (int d = 32; d >= 1; d >>= 1){ s += __shfl_xor(s, d); q += __shfl_xor(q, d); }
  __shared__ float ss[4], qq[4];
  int wv = t >> 6, ln = t & 63;
  if (ln == 0){ ss[wv] = s; qq[wv] = q; }
  __syncthreads();
  s = ss[0] + ss[1] + ss[2] + ss[3];
  q = qq[0] + qq[1] + qq[2] + qq[3];
  float m = s*(1.f/1024.f);
  float var = q*(1.f/1024.f) - m*m;
  float r = rsqrtf(var + 1e-5f);
  int c = t*4;
  ushort4 pk = make_ushort4(
      f2bu((v.x - m)*r*w[c]   + bias[c]),
      f2bu((v.y - m)*r*w[c+1] + bias[c+1]),
      f2bu((v.z - m)*r*w[c+2] + bias[c+2]),
      f2bu((v.w - m)*r*w[c+3] + bias[c+3]));
  *reinterpret_cast<ushort4*>(y4 + (size_t)row*1024 + c) = pk;
}

// ---------------- residual 2 + transpose: out(B,C,N) = x1 + g2*m ----------------
__global__ void k_resid2(const float* __restrict__ x1, const bf16* __restrict__ Mb,
                         const float* __restrict__ g2, float* __restrict__ out){
  int b = blockIdx.z, c0 = blockIdx.y*64, n0 = blockIdx.x*64;
  __shared__ float t[64][65];   // [c_local][n_local]
  int i = threadIdx.x & 63, j0 = (threadIdx.x >> 6)*16;
  float g = g2[c0 + i];
  #pragma unroll
  for (int r = 0; r < 16; ++r){
    size_t off = ((size_t)b*1024 + n0 + j0 + r)*1024 + c0 + i;
    t[i][j0 + r] = x1[off] + g*b2f(Mb[off]);
  }
  __syncthreads();
  int j = threadIdx.x & 63, i0 = (threadIdx.x >> 6)*16;
  #pragma unroll
  for (int r = 0; r < 16; ++r)
    out[((size_t)b*1024 + c0 + i0 + r)*1024 + n0 + j] = t[i0 + r][j];
}

extern "C" void kernel_launch(void* const* d_in, const int* in_sizes, int n_in,
                              void* d_out, int out_size, void* d_ws, size_t ws_size,
                              hipStream_t stream){
  (void)in_sizes; (void)n_in; (void)out_size; (void)ws_size;
  const float* x      = (const float*)d_in[0];
  const float* ln1_w  = (const float*)d_in[1];
  const float* ln1_b  = (const float*)d_in[2];
  const float* Wattn  = (const float*)d_in[3];
  const float* Wproj  = (const float*)d_in[4];
  const float* temp   = (const float*)d_in[5];
  const float* dbias  = (const float*)d_in[6];
  const float* ln2_w  = (const float*)d_in[7];
  const float* ln2_b  = (const float*)d_in[8];
  const float* W1     = (const float*)d_in[9];
  const float* b1     = (const float*)d_in[10];
  const float* W2     = (const float*)d_in[11];
  const float* b2     = (const float*)d_in[12];
  const float* g1     = (const float*)d_in[13];
  const float* g2     = (const float*)d_in[14];
  float* out = (float*)d_out;

  size_t off = 0;
  char* wsb = (char*)d_ws;
  auto alloc = [&](size_t bytes)->char*{
    char* p = wsb + off; off += (bytes + 255) & ~(size_t)255; return p;
  };
  bf16*  Y3  = (bf16*)alloc((size_t)16384*1024*2);   // also Y4 (LN2 out)
  bf16*  Wb  = (bf16*)alloc((size_t)16384*1024*2);   // also Ab; also H-half lo
  bf16*  Yb  = (bf16*)alloc((size_t)16384*1024*2);   // TSSA y; also H-half hi
  bf16*  Mb  = (bf16*)alloc((size_t)16384*1024*2);   // MLP-down accum (bf16)
  float* x1  = (float*)alloc((size_t)16384*1024*4);
  bf16*  WAb = (bf16*)alloc((size_t)1024*1024*2);
  bf16*  WPb = (bf16*)alloc((size_t)1024*1024*2);
  bf16*  W1b = (bf16*)alloc((size_t)4096*1024*2);
  bf16*  W2b = (bf16*)alloc((size_t)4096*1024*2);
  float* mu  = (float*)alloc((size_t)16384*4);
  float* rs  = (float*)alloc((size_t)16384*4);
  float* S   = (float*)alloc((size_t)2048*128*4);
  float* tmp = (float*)alloc((size_t)16*8*1024*4);
  float* Pi  = (float*)alloc((size_t)16*8*1024*4);
  float* Pc  = (float*)alloc((size_t)16*8*1024*4);
  float* Ps  = (float*)alloc((size_t)16*64*1024*4);
  float* Pq  = (float*)alloc((size_t)16*64*1024*4);

  dim3 b256(256), b128(128);

  // weights -> bf16
  k_f2b<<<dim3((1024*1024/4 + 255)/256), b256, 0, stream>>>(Wattn, WAb, 1024*1024);
  k_f2b<<<dim3((1024*1024/4 + 255)/256), b256, 0, stream>>>(Wproj, WPb, 1024*1024);
  k_f2b<<<dim3((4096*1024/4 + 255)/256), b256, 0, stream>>>(W1, W1b, 4096*1024);
  k_f2b<<<dim3((4096*1024/4 + 255)/256), b256, 0, stream>>>(W2, W2b, 4096*1024);

  // LN1 stats (two-phase, coalesced)
  k_ln1_part<<<dim3(64, 16), b256, 0, stream>>>(x, Ps, Pq);
  k_ln1_finish<<<dim3(4, 16), b256, 0, stream>>>(Ps, Pq, mu, rs);
  k_ln1_apply<<<dim3(16, 16, 16), b256, 0, stream>>>(x, mu, rs, ln1_w, ln1_b, Y3);

  // c_attn
  k_gemm<0><<<dim3(8*128), b256, 0, stream>>>(Y3, WAb, Wb, nullptr,
                                              16384, 1024, 1024, 1024, 1024, 1024, 8);

  // TSSA elementwise chain
  k_chunksum<false><<<dim3(2048), b128, 0, stream>>>(Wb, nullptr, S);
  k_stageA<<<dim3(2048), b128, 0, stream>>>(Wb, S, temp, dbias, tmp);
  k_softmax_scan<<<dim3(128), b256, 0, stream>>>(tmp, Pi, Pc);
  k_chunksum<true><<<dim3(2048), b128, 0, stream>>>(Wb, Pi, S);
  k_stageC<<<dim3(2048), b128, 0, stream>>>(Wb, S, Pi, Pc, Yb);

  // c_proj (writes into Wb slab, now free)
  bf16* Ab = Wb;
  k_gemm<0><<<dim3(8*128), b256, 0, stream>>>(Yb, WPb, Ab, nullptr,
                                              16384, 1024, 1024, 1024, 1024, 1024, 8);

  // residual 1 (x is (B,C,N); x1 is (B,N,C) fp32)
  k_resid1<<<dim3(16, 16, 16), b256, 0, stream>>>(x, Ab, g1, x1);

  // LN2 -> Y4 (reuse Y3 slab)
  k_ln2<<<dim3(16384), b256, 0, stream>>>(x1, ln2_w, ln2_b, Y3);

  // MLP chunked over hidden dim F (2 x 2048): H-half (64 MB) overlays the
  // contiguous dead [Wb|Yb] slabs -> zero extra workspace, full grids.
  // Down-GEMM accumulates across halves via bf16 RMW of Mb (EPI 3).
  bf16* Hb = Wb;   // 64 MB span: Wb (32 MB) + Yb (32 MB), both dead here
  for (int f = 0; f < 2; ++f){
    k_gemm<1><<<dim3(16*128), b256, 0, stream>>>(Y3, W1b + (size_t)f*2048*1024, Hb,
                                                 b1 + f*2048,
                                                 16384, 2048, 1024, 1024, 1024, 2048, 16);
    if (f == 0)
      k_gemm<0><<<dim3(8*128), b256, 0, stream>>>(Hb, W2b + f*2048, Mb, nullptr,
                                                  16384, 1024, 2048, 2048, 4096, 1024, 8);
    else
      k_gemm<3><<<dim3(8*128), b256, 0, stream>>>(Hb, W2b + f*2048, Mb, b2,
                                                  16384, 1024, 2048, 2048, 4096, 1024, 8);
  }

  // residual 2 + transpose to (B,C,H,W)
  k_resid2<<<dim3(16, 16, 16), b256, 0, stream>>>(x1, Mb, g2, out);
}

// Round 5
// 631.115 us; speedup vs baseline: 1.5980x; 1.1196x over previous
//
#include <hip/hip_runtime.h>
#include <hip/hip_bf16.h>
#include <math.h>

using bf16 = __hip_bfloat16;
typedef __bf16 bf16x8 __attribute__((ext_vector_type(8)));
typedef float f32x4 __attribute__((ext_vector_type(4)));

#define EPS16F 0.0009765625f

__device__ __forceinline__ float b2f(bf16 v){ return __bfloat162float(v); }
__device__ __forceinline__ bf16  f2b(float f){ return __float2bfloat16(f); }
__device__ __forceinline__ unsigned short f2bu(float f){
  bf16 h = __float2bfloat16(f); return __builtin_bit_cast(unsigned short, h);
}

__device__ __forceinline__ void gload16(const void* g, void* l){
  __builtin_amdgcn_global_load_lds((const __attribute__((address_space(1))) void*)g,
                                   (__attribute__((address_space(3))) void*)l, 16, 0, 0);
}

// inline-asm LDS vector read (so manual lgkmcnt discipline applies)
__device__ __forceinline__ bf16x8 dsr(const void* p){
  bf16x8 d;
  asm volatile("ds_read_b128 %0, %1"
               : "=v"(d)
               : "v"((const __attribute__((address_space(3))) void*)p));
  return d;
}

// ---------------- fp32 -> bf16 convert ----------------
__global__ void k_f2b(const float* __restrict__ in, bf16* __restrict__ out, int n){
  int i = (blockIdx.x*blockDim.x + threadIdx.x)*4;
  if (i + 3 < n){
    float4 v = *(const float4*)(in + i);
    ushort4 pk = make_ushort4(f2bu(v.x), f2bu(v.y), f2bu(v.z), f2bu(v.w));
    *reinterpret_cast<ushort4*>(out + i) = pk;
  } else {
    for (; i < n; ++i) out[i] = f2b(in[i]);
  }
}

// ---------------- LN1 stats phase 1 ----------------
__global__ void __launch_bounds__(256) k_ln1_part(const float* __restrict__ x,
                                                  float* __restrict__ Ps,
                                                  float* __restrict__ Pq){
  int chunk = blockIdx.x, b = blockIdx.y;
  int t = threadIdx.x;
  const float4* xp = (const float4*)(x + ((size_t)b*1024 + chunk*16)*1024) + t;
  float4 s = {0.f,0.f,0.f,0.f}, q = {0.f,0.f,0.f,0.f};
  #pragma unroll
  for (int c = 0; c < 16; ++c){
    float4 v = xp[c*256];
    s.x += v.x; s.y += v.y; s.z += v.z; s.w += v.w;
    q.x += v.x*v.x; q.y += v.y*v.y; q.z += v.z*v.z; q.w += v.w*v.w;
  }
  size_t o = ((size_t)(b*64 + chunk))*256 + t;
  ((float4*)Ps)[o] = s;
  ((float4*)Pq)[o] = q;
}

// ---------------- LN1 stats phase 2 ----------------
__global__ void __launch_bounds__(256) k_ln1_finish(const float* __restrict__ Ps,
                                                    const float* __restrict__ Pq,
                                                    float* __restrict__ mu,
                                                    float* __restrict__ rs){
  int nb = blockIdx.x, b = blockIdx.y;
  int n = nb*256 + threadIdx.x;
  const float* ps = Ps + (size_t)b*64*1024 + n;
  const float* pq = Pq + (size_t)b*64*1024 + n;
  float S = 0.f, Q = 0.f;
  #pragma unroll 8
  for (int c = 0; c < 64; ++c){ S += ps[(size_t)c*1024]; Q += pq[(size_t)c*1024]; }
  float m = S*(1.f/1024.f);
  float var = Q*(1.f/1024.f) - m*m;
  mu[b*1024 + n] = m;
  rs[b*1024 + n] = rsqrtf(var + 1e-5f);
}

// ---------------- LN1 apply + transpose ----------------
__global__ void k_ln1_apply(const float* __restrict__ x, const float* __restrict__ mu,
                            const float* __restrict__ rs, const float* __restrict__ w,
                            const float* __restrict__ bias, bf16* __restrict__ y3){
  int b = blockIdx.z, c0 = blockIdx.y*64, n0 = blockIdx.x*64;
  __shared__ float t[64][65];
  int j = threadIdx.x & 63, i0 = (threadIdx.x >> 6)*16;
  const float* xp = x + ((size_t)b*1024 + c0)*1024 + n0;
  #pragma unroll
  for (int r = 0; r < 16; ++r)
    t[j][i0 + r] = xp[(size_t)(i0 + r)*1024 + j];
  __syncthreads();
  int i = threadIdx.x & 63, jj0 = (threadIdx.x >> 6)*16;
  float wc = w[c0 + i], bc = bias[c0 + i];
  bf16* yp = y3 + ((size_t)b*1024 + n0)*1024 + c0 + i;
  #pragma unroll
  for (int r = 0; r < 16; ++r){
    int n = n0 + jj0 + r;
    float v = t[jj0 + r][i];
    yp[(size_t)(jj0 + r)*1024] = f2b((v - mu[b*1024 + n])*rs[b*1024 + n]*wc + bc);
  }
}

// ================= 256x256 8-phase GEMM =================
// out(M,N) = A(M,K) * W(N,K)^T, bf16. 512 thr (8 waves 2Mx4N), BK=64.
// LDS: 4-slot ring (32KB each: A[256][32] + B[256][32] bf16), chunk-XOR swizzle.
// Per K-tile: 4 phases (m-half x K-half), 16 MFMA each; each phase stages one
// half-panel of tile t+1 into slots (s+2,s+3); vmcnt(4) at even phases only.
// EPI: 0 plain, 1 +bias+gelu, 3 +bias+accumulate-into-out
#define PHASE(J_, MH, STAGE_STMT, VM)                                          \
  {                                                                            \
    if ((MH) == 0){                                                            \
      unsigned sb = (J_)*32768u + 16384u + (unsigned)((wc*64 + lr)*64) + cswz; \
      b[0] = dsr(smem + sb);        b[1] = dsr(smem + sb + 1024);              \
      b[2] = dsr(smem + sb + 2048); b[3] = dsr(smem + sb + 3072);              \
    }                                                                          \
    {                                                                          \
      unsigned sa = (J_)*32768u + (unsigned)((wr*128 + (MH)*64 + lr)*64) + cswz;\
      a[0] = dsr(smem + sa);        a[1] = dsr(smem + sa + 1024);              \
      a[2] = dsr(smem + sa + 2048); a[3] = dsr(smem + sa + 3072);              \
    }                                                                          \
    STAGE_STMT;                                                                \
    if (VM) asm volatile("s_waitcnt vmcnt(4)" ::: "memory");                   \
    __builtin_amdgcn_s_barrier();                                              \
    asm volatile("s_waitcnt lgkmcnt(0)" ::: "memory");                         \
    __builtin_amdgcn_sched_barrier(0);                                         \
    __builtin_amdgcn_s_setprio(1);                                             \
    _Pragma("unroll")                                                          \
    for (int i_ = 0; i_ < 4; ++i_)                                             \
      _Pragma("unroll")                                                        \
      for (int n_ = 0; n_ < 4; ++n_)                                           \
        acc[(MH)*4 + i_][n_] = __builtin_amdgcn_mfma_f32_16x16x32_bf16(        \
            a[i_], b[n_], acc[(MH)*4 + i_][n_], 0, 0, 0);                      \
    __builtin_amdgcn_s_setprio(0);                                             \
    __builtin_amdgcn_s_barrier();                                              \
  }

template<int EPI>
__global__ void __launch_bounds__(512, 2) k_gemm8(const bf16* __restrict__ A,
                                                  const bf16* __restrict__ W,
                                                  bf16* __restrict__ out,
                                                  const float* __restrict__ bias,
                                                  int K, int lda, int ldw, int ldo,
                                                  int nbx){
  __shared__ __align__(16) char smem[131072];
  int nwg = gridDim.x;
  int cpx = nwg >> 3;
  int bid = blockIdx.x;
  int swz = (bid & 7)*cpx + (bid >> 3);
  int bx = swz % nbx, by = swz / nbx;
  int m0 = by*256, n0 = bx*256;
  int t = threadIdx.x;
  int lane = t & 63, wave = t >> 6;
  int wr = wave >> 2, wc = wave & 3;     // 2x4 waves; each owns 128x64
  int lr = lane & 15, lg = lane >> 4;
  unsigned cswz = (unsigned)((lg ^ ((lr >> 1) & 3))*16);
  int srow = t >> 2;                      // staging: row within half-panel
  int sg = (t & 3) ^ ((t >> 3) & 3);      // staging: swizzled source chunk
  f32x4 acc[8][4] = {};
  bf16x8 a[4], b[4];
  int nt = K >> 6;

  // stage one half-panel (256 rows x 32 k) = 2 gload16/thread
  auto stage = [&](const bf16* g, int ld, int r0, int gk, unsigned lbase){
    const bf16* s0 = g + (size_t)(r0 + srow)*ld + gk + sg*8;
    gload16(s0, smem + lbase + t*16);
    gload16(s0 + (size_t)128*ld, smem + lbase + 8192 + t*16);
  };

  // prologue: tile 0 into slots 0 (K-half0) and 1 (K-half1)
  stage(A, lda, m0, 0,  0u);
  stage(W, ldw, n0, 0,  16384u);
  stage(A, lda, m0, 32, 32768u);
  stage(W, ldw, n0, 32, 32768u + 16384u);
  asm volatile("s_waitcnt vmcnt(4)" ::: "memory");
  __builtin_amdgcn_s_barrier();

  for (int tt = 0; tt < nt; ++tt){
    unsigned sl  = ((unsigned)tt*2) & 3;
    unsigned sl1 = (sl + 1) & 3;
    unsigned sn0 = (sl + 2) & 3;
    unsigned sn1 = (sl + 3) & 3;
    int kn = (tt + 1 < nt) ? (tt + 1)*64 : 0;
    PHASE(sl,  0, stage(A, lda, m0, kn,      sn0*32768u),           0)
    PHASE(sl,  1, stage(W, ldw, n0, kn,      sn0*32768u + 16384u),  1)
    PHASE(sl1, 0, stage(A, lda, m0, kn + 32, sn1*32768u),           0)
    PHASE(sl1, 1, stage(W, ldw, n0, kn + 32, sn1*32768u + 16384u),  1)
  }

  #pragma unroll
  for (int m = 0; m < 8; ++m){
    #pragma unroll
    for (int n = 0; n < 4; ++n){
      int col = n0 + wc*64 + n*16 + lr;
      #pragma unroll
      for (int j = 0; j < 4; ++j){
        int row = m0 + wr*128 + m*16 + lg*4 + j;
        size_t idx = (size_t)row*ldo + col;
        float v = acc[m][n][j];
        if (EPI >= 1) v += bias[col];
        if (EPI == 1) v = 0.5f*v*(1.0f + erff(v*0.70710678118654752f));
        if (EPI == 3) v += b2f(out[idx]);
        out[idx] = f2b(v);
      }
    }
  }
}

// ---------------- chunk partial sums of w^2 (optionally * Pi) ----------------
template<bool WEIGHTED>
__global__ void k_chunksum(const bf16* __restrict__ Wb, const float* __restrict__ Pi,
                           float* __restrict__ S){
  int blk = blockIdx.x;
  int ch = blk & 15, h = (blk >> 4) & 7, b = blk >> 7;
  int dd = threadIdx.x;
  const bf16* wp = Wb + ((size_t)(b*1024) + ch*64)*1024 + h*128 + dd;
  float acc = 0.f;
  #pragma unroll 8
  for (int i = 0; i < 64; ++i){
    float w = b2f(wp[(size_t)i*1024]);
    float sq = w*w;
    if (WEIGHTED) sq *= Pi[(size_t)(b*8 + h)*1024 + ch*64 + i];
    acc += sq;
  }
  S[(size_t)blk*128 + dd] = acc;
}

// ---------------- stage A: running denom -> tmp(b,h,n) ----------------
__global__ void k_stageA(const bf16* __restrict__ Wb, const float* __restrict__ S1,
                         const float* __restrict__ temp, const float* __restrict__ dbias,
                         float* __restrict__ tmp){
  int blk = blockIdx.x;
  int ch = blk & 15, h = (blk >> 4) & 7, b = blk >> 7;
  int dd = threadIdx.x;
  const float* sp = S1 + (size_t)(b*8 + h)*16*128 + dd;
  float base = 0.f;
  for (int c = 0; c < ch; ++c) base += sp[(size_t)c*128];
  __shared__ float V[64][129];
  const bf16* wp = Wb + ((size_t)(b*1024) + ch*64)*1024 + h*128 + dd;
  float run = base;
  for (int i = 0; i < 64; ++i){
    float w = b2f(wp[(size_t)i*1024]);
    float sq = w*w;
    run += sq;
    V[i][dd] = sq / fmaxf(run, EPS16F);
  }
  __syncthreads();
  int tt = threadIdx.x;
  int n_loc = tt >> 1, half = tt & 1;
  float s = 0.f;
  for (int k = 0; k < 64; ++k) s += V[n_loc][half*64 + k];
  s += __shfl_xor(s, 1);
  if (half == 0){
    int n = ch*64 + n_loc;
    float db = dbias[h*1024 + n];
    tmp[(size_t)(b*8 + h)*1024 + n] = (s + 128.f*db)*temp[h];
  }
}

// ---------------- softmax over heads + inclusive scan of Pi over n ----------------
__global__ void k_softmax_scan(const float* __restrict__ tmp, float* __restrict__ Pi,
                               float* __restrict__ Pc){
  int bh = blockIdx.x; int b = bh >> 3, h = bh & 7;
  int t = threadIdx.x;
  const float* tp = tmp + (size_t)b*8*1024;
  float p[4];
  #pragma unroll
  for (int i = 0; i < 4; ++i){
    int n = t*4 + i;
    float v[8]; float mx = -1e30f;
    #pragma unroll
    for (int hh = 0; hh < 8; ++hh){ v[hh] = tp[hh*1024 + n]; mx = fmaxf(mx, v[hh]); }
    float Z = 0.f;
    #pragma unroll
    for (int hh = 0; hh < 8; ++hh) Z += expf(v[hh] - mx);
    p[i] = expf(v[h] - mx)/Z;
    Pi[(size_t)bh*1024 + n] = p[i];
  }
  float l0 = p[0], l1 = l0 + p[1], l2 = l1 + p[2], l3 = l2 + p[3];
  float ts = l3, sc = ts;
  int ln = t & 63, wv = t >> 6;
  #pragma unroll
  for (int d = 1; d < 64; d <<= 1){
    float o = __shfl_up(sc, d);
    if (ln >= d) sc += o;
  }
  __shared__ float wsum[4];
  if (ln == 63) wsum[wv] = sc;
  __syncthreads();
  float woff = 0.f;
  for (int w2 = 0; w2 < 4; ++w2) if (w2 < wv) woff += wsum[w2];
  float excl = woff + sc - ts;
  size_t o4 = (size_t)bh*1024 + t*4;
  Pc[o4]   = excl + l0;
  Pc[o4+1] = excl + l1;
  Pc[o4+2] = excl + l2;
  Pc[o4+3] = excl + l3;
}

// ---------------- stage C: dots -> y (B,N,O) bf16 ----------------
__global__ void k_stageC(const bf16* __restrict__ Wb, const float* __restrict__ S2,
                         const float* __restrict__ Pi, const float* __restrict__ Pc,
                         bf16* __restrict__ Y){
  int blk = blockIdx.x;
  int ch = blk & 15, h = (blk >> 4) & 7, b = blk >> 7;
  int dd = threadIdx.x;
  const float* sp = S2 + (size_t)(b*8 + h)*16*128 + dd;
  float base = 0.f;
  for (int c = 0; c < ch; ++c) base += sp[(size_t)c*128];
  const bf16* wp = Wb + ((size_t)(b*1024) + ch*64)*1024 + h*128 + dd;
  bf16* yp = Y + ((size_t)(b*1024) + ch*64)*1024 + h*128 + dd;
  const float* pip = Pi + (size_t)(b*8 + h)*1024 + ch*64;
  const float* pcp = Pc + (size_t)(b*8 + h)*1024 + ch*64;
  float run = base;
  for (int i = 0; i < 64; ++i){
    float w = b2f(wp[(size_t)i*1024]);
    float sq = w*w;
    float pi = pip[i];
    run += sq*pi;
    float dots = run / (pcp[i] + EPS16F);
    float at = 1.0f/(1.0f + dots);
    yp[(size_t)i*1024] = f2b(-(w*pi)*at);
  }
}

// ---------------- residual 1: x1(B,N,C) = xT + g1 * a ----------------
__global__ void k_resid1(const float* __restrict__ x, const bf16* __restrict__ Ab,
                         const float* __restrict__ g1, float* __restrict__ x1){
  int b = blockIdx.z, c0 = blockIdx.y*64, n0 = blockIdx.x*64;
  __shared__ float t[64][65];
  int j = threadIdx.x & 63, i0 = (threadIdx.x >> 6)*16;
  const float* xp = x + ((size_t)b*1024 + c0)*1024 + n0;
  #pragma unroll
  for (int r = 0; r < 16; ++r)
    t[j][i0 + r] = xp[(size_t)(i0 + r)*1024 + j];
  __syncthreads();
  int i = threadIdx.x & 63, jj0 = (threadIdx.x >> 6)*16;
  float g = g1[c0 + i];
  #pragma unroll
  for (int r = 0; r < 16; ++r){
    size_t off = ((size_t)b*1024 + n0 + jj0 + r)*1024 + c0 + i;
    x1[off] = t[jj0 + r][i] + g*b2f(Ab[off]);
  }
}

// ---------------- LN2 fused (row-contig) -> Y4 bf16 ----------------
__global__ void k_ln2(const float* __restrict__ x1, const float* __restrict__ w,
                      const float* __restrict__ bias, bf16* __restrict__ y4){
  int row = blockIdx.x, t = threadIdx.x;
  const float4* rp = (const float4*)(x1 + (size_t)row*1024);
  float4 v = rp[t];
  float s = v.x + v.y + v.z + v.w;
  float q = v.x*v.x + v.y*v.y + v.z*v.z + v.w*v.w;
  #pragma unroll
  for (int d = 32; d >= 1; d >>= 1){ s += __shfl_xor(s, d); q += __shfl_xor(q, d); }
  __shared__ float ss[4], qq[4];
  int wv = t >> 6, ln = t & 63;
  if (ln == 0){ ss[wv] = s; qq[wv] = q; }
  __syncthreads();
  s = ss[0] + ss[1] + ss[2] + ss[3];
  q = qq[0] + qq[1] + qq[2] + qq[3];
  float m = s*(1.f/1024.f);
  float var = q*(1.f/1024.f) - m*m;
  float r = rsqrtf(var + 1e-5f);
  int c = t*4;
  ushort4 pk = make_ushort4(
      f2bu((v.x - m)*r*w[c]   + bias[c]),
      f2bu((v.y - m)*r*w[c+1] + bias[c+1]),
      f2bu((v.z - m)*r*w[c+2] + bias[c+2]),
      f2bu((v.w - m)*r*w[c+3] + bias[c+3]));
  *reinterpret_cast<ushort4*>(y4 + (size_t)row*1024 + c) = pk;
}

// ---------------- residual 2 + transpose: out(B,C,N) = x1 + g2*m ----------------
__global__ void k_resid2(const float* __restrict__ x1, const bf16* __restrict__ Mb,
                         const float* __restrict__ g2, float* __restrict__ out){
  int b = blockIdx.z, c0 = blockIdx.y*64, n0 = blockIdx.x*64;
  __shared__ float t[64][65];
  int i = threadIdx.x & 63, j0 = (threadIdx.x >> 6)*16;
  float g = g2[c0 + i];
  #pragma unroll
  for (int r = 0; r < 16; ++r){
    size_t off = ((size_t)b*1024 + n0 + j0 + r)*1024 + c0 + i;
    t[i][j0 + r] = x1[off] + g*b2f(Mb[off]);
  }
  __syncthreads();
  int j = threadIdx.x & 63, i0 = (threadIdx.x >> 6)*16;
  #pragma unroll
  for (int r = 0; r < 16; ++r)
    out[((size_t)b*1024 + c0 + i0 + r)*1024 + n0 + j] = t[i0 + r][j];
}

extern "C" void kernel_launch(void* const* d_in, const int* in_sizes, int n_in,
                              void* d_out, int out_size, void* d_ws, size_t ws_size,
                              hipStream_t stream){
  (void)in_sizes; (void)n_in; (void)out_size; (void)ws_size;
  const float* x      = (const float*)d_in[0];
  const float* ln1_w  = (const float*)d_in[1];
  const float* ln1_b  = (const float*)d_in[2];
  const float* Wattn  = (const float*)d_in[3];
  const float* Wproj  = (const float*)d_in[4];
  const float* temp   = (const float*)d_in[5];
  const float* dbias  = (const float*)d_in[6];
  const float* ln2_w  = (const float*)d_in[7];
  const float* ln2_b  = (const float*)d_in[8];
  const float* W1     = (const float*)d_in[9];
  const float* b1     = (const float*)d_in[10];
  const float* W2     = (const float*)d_in[11];
  const float* b2     = (const float*)d_in[12];
  const float* g1     = (const float*)d_in[13];
  const float* g2     = (const float*)d_in[14];
  float* out = (float*)d_out;

  size_t off = 0;
  char* wsb = (char*)d_ws;
  auto alloc = [&](size_t bytes)->char*{
    char* p = wsb + off; off += (bytes + 255) & ~(size_t)255; return p;
  };
  bf16*  Y3  = (bf16*)alloc((size_t)16384*1024*2);   // also Y4 (LN2 out)
  bf16*  Wb  = (bf16*)alloc((size_t)16384*1024*2);   // also Ab; also H-half lo
  bf16*  Yb  = (bf16*)alloc((size_t)16384*1024*2);   // TSSA y; also H-half hi
  bf16*  Mb  = (bf16*)alloc((size_t)16384*1024*2);   // MLP-down accum (bf16)
  float* x1  = (float*)alloc((size_t)16384*1024*4);
  bf16*  WAb = (bf16*)alloc((size_t)1024*1024*2);
  bf16*  WPb = (bf16*)alloc((size_t)1024*1024*2);
  bf16*  W1b = (bf16*)alloc((size_t)4096*1024*2);
  bf16*  W2b = (bf16*)alloc((size_t)4096*1024*2);
  float* mu  = (float*)alloc((size_t)16384*4);
  float* rs  = (float*)alloc((size_t)16384*4);
  float* S   = (float*)alloc((size_t)2048*128*4);
  float* tmp = (float*)alloc((size_t)16*8*1024*4);
  float* Pi  = (float*)alloc((size_t)16*8*1024*4);
  float* Pc  = (float*)alloc((size_t)16*8*1024*4);
  float* Ps  = (float*)alloc((size_t)16*64*1024*4);
  float* Pq  = (float*)alloc((size_t)16*64*1024*4);

  dim3 b256(256), b128(128), b512(512);

  // weights -> bf16
  k_f2b<<<dim3((1024*1024/4 + 255)/256), b256, 0, stream>>>(Wattn, WAb, 1024*1024);
  k_f2b<<<dim3((1024*1024/4 + 255)/256), b256, 0, stream>>>(Wproj, WPb, 1024*1024);
  k_f2b<<<dim3((4096*1024/4 + 255)/256), b256, 0, stream>>>(W1, W1b, 4096*1024);
  k_f2b<<<dim3((4096*1024/4 + 255)/256), b256, 0, stream>>>(W2, W2b, 4096*1024);

  // LN1 stats (two-phase, coalesced)
  k_ln1_part<<<dim3(64, 16), b256, 0, stream>>>(x, Ps, Pq);
  k_ln1_finish<<<dim3(4, 16), b256, 0, stream>>>(Ps, Pq, mu, rs);
  k_ln1_apply<<<dim3(16, 16, 16), b256, 0, stream>>>(x, mu, rs, ln1_w, ln1_b, Y3);

  // c_attn: (16384,1024,1024) -> 64x4 = 256 blocks
  k_gemm8<0><<<dim3(256), b512, 0, stream>>>(Y3, WAb, Wb, nullptr,
                                             1024, 1024, 1024, 1024, 4);

  // TSSA elementwise chain
  k_chunksum<false><<<dim3(2048), b128, 0, stream>>>(Wb, nullptr, S);
  k_stageA<<<dim3(2048), b128, 0, stream>>>(Wb, S, temp, dbias, tmp);
  k_softmax_scan<<<dim3(128), b256, 0, stream>>>(tmp, Pi, Pc);
  k_chunksum<true><<<dim3(2048), b128, 0, stream>>>(Wb, Pi, S);
  k_stageC<<<dim3(2048), b128, 0, stream>>>(Wb, S, Pi, Pc, Yb);

  // c_proj (writes into Wb slab, now free)
  bf16* Ab = Wb;
  k_gemm8<0><<<dim3(256), b512, 0, stream>>>(Yb, WPb, Ab, nullptr,
                                             1024, 1024, 1024, 1024, 4);

  // residual 1 (x is (B,C,N); x1 is (B,N,C) fp32)
  k_resid1<<<dim3(16, 16, 16), b256, 0, stream>>>(x, Ab, g1, x1);

  // LN2 -> Y4 (reuse Y3 slab)
  k_ln2<<<dim3(16384), b256, 0, stream>>>(x1, ln2_w, ln2_b, Y3);

  // MLP chunked over hidden dim F (2 x 2048); H-half overlays dead [Wb|Yb].
  bf16* Hb = Wb;
  for (int f = 0; f < 2; ++f){
    // up: (16384,2048,1024) -> 64x8 = 512 blocks
    k_gemm8<1><<<dim3(512), b512, 0, stream>>>(Y3, W1b + (size_t)f*2048*1024, Hb,
                                               b1 + f*2048, 1024, 1024, 1024, 2048, 8);
    // down: (16384,1024,2048) -> 256 blocks; f=1 accumulates + bias
    if (f == 0)
      k_gemm8<0><<<dim3(256), b512, 0, stream>>>(Hb, W2b + f*2048, Mb, nullptr,
                                                 2048, 2048, 4096, 1024, 4);
    else
      k_gemm8<3><<<dim3(256), b512, 0, stream>>>(Hb, W2b + f*2048, Mb, b2,
                                                 2048, 2048, 4096, 1024, 4);
  }

  // residual 2 + transpose to (B,C,H,W)
  k_resid2<<<dim3(16, 16, 16), b256, 0, stream>>>(x1, Mb, g2, out);
}

// Round 7
// 586.264 us; speedup vs baseline: 1.7202x; 1.0765x over previous
//
#include <hip/hip_runtime.h>
#include <hip/hip_bf16.h>
#include <math.h>

using bf16 = __hip_bfloat16;
typedef __bf16 bf16x8 __attribute__((ext_vector_type(8)));
typedef float f32x4 __attribute__((ext_vector_type(4)));

#define EPS16F 0.0009765625f

__device__ __forceinline__ float b2f(bf16 v){ return __bfloat162float(v); }
__device__ __forceinline__ bf16  f2b(float f){ return __float2bfloat16(f); }
__device__ __forceinline__ unsigned short f2bu(float f){
  bf16 h = __float2bfloat16(f); return __builtin_bit_cast(unsigned short, h);
}

__device__ __forceinline__ void gload16(const void* g, void* l){
  __builtin_amdgcn_global_load_lds((const __attribute__((address_space(1))) void*)g,
                                   (__attribute__((address_space(3))) void*)l, 16, 0, 0);
}

typedef const __attribute__((address_space(3))) char* lds_cp;

// LDS vector read with compile-time immediate offset (must be < 65536)
template<unsigned OFF>
__device__ __forceinline__ bf16x8 dsr(lds_cp p){
  static_assert(OFF < 65536u, "ds_read offset is 16-bit");
  bf16x8 d;
  asm volatile("ds_read_b128 %0, %1 offset:%c2"
               : "=v"(d) : "v"(p), "i"(OFF));
  return d;
}

// ---------------- fp32 -> bf16 convert ----------------
__global__ void k_f2b(const float* __restrict__ in, bf16* __restrict__ out, int n){
  int i = (blockIdx.x*blockDim.x + threadIdx.x)*4;
  if (i + 3 < n){
    float4 v = *(const float4*)(in + i);
    ushort4 pk = make_ushort4(f2bu(v.x), f2bu(v.y), f2bu(v.z), f2bu(v.w));
    *reinterpret_cast<ushort4*>(out + i) = pk;
  } else {
    for (; i < n; ++i) out[i] = f2b(in[i]);
  }
}

// ---------------- LN1 stats phase 1 ----------------
__global__ void __launch_bounds__(256) k_ln1_part(const float* __restrict__ x,
                                                  float* __restrict__ Ps,
                                                  float* __restrict__ Pq){
  int chunk = blockIdx.x, b = blockIdx.y;
  int t = threadIdx.x;
  const float4* xp = (const float4*)(x + ((size_t)b*1024 + chunk*16)*1024) + t;
  float4 s = {0.f,0.f,0.f,0.f}, q = {0.f,0.f,0.f,0.f};
  #pragma unroll
  for (int c = 0; c < 16; ++c){
    float4 v = xp[c*256];
    s.x += v.x; s.y += v.y; s.z += v.z; s.w += v.w;
    q.x += v.x*v.x; q.y += v.y*v.y; q.z += v.z*v.z; q.w += v.w*v.w;
  }
  size_t o = ((size_t)(b*64 + chunk))*256 + t;
  ((float4*)Ps)[o] = s;
  ((float4*)Pq)[o] = q;
}

// ---------------- LN1 stats phase 2 ----------------
__global__ void __launch_bounds__(256) k_ln1_finish(const float* __restrict__ Ps,
                                                    const float* __restrict__ Pq,
                                                    float* __restrict__ mu,
                                                    float* __restrict__ rs){
  int nb = blockIdx.x, b = blockIdx.y;
  int n = nb*256 + threadIdx.x;
  const float* ps = Ps + (size_t)b*64*1024 + n;
  const float* pq = Pq + (size_t)b*64*1024 + n;
  float S = 0.f, Q = 0.f;
  #pragma unroll 8
  for (int c = 0; c < 64; ++c){ S += ps[(size_t)c*1024]; Q += pq[(size_t)c*1024]; }
  float m = S*(1.f/1024.f);
  float var = Q*(1.f/1024.f) - m*m;
  mu[b*1024 + n] = m;
  rs[b*1024 + n] = rsqrtf(var + 1e-5f);
}

// ---------------- LN1 apply + transpose ----------------
__global__ void k_ln1_apply(const float* __restrict__ x, const float* __restrict__ mu,
                            const float* __restrict__ rs, const float* __restrict__ w,
                            const float* __restrict__ bias, bf16* __restrict__ y3){
  int b = blockIdx.z, c0 = blockIdx.y*64, n0 = blockIdx.x*64;
  __shared__ float t[64][65];
  int j = threadIdx.x & 63, i0 = (threadIdx.x >> 6)*16;
  const float* xp = x + ((size_t)b*1024 + c0)*1024 + n0;
  #pragma unroll
  for (int r = 0; r < 16; ++r)
    t[j][i0 + r] = xp[(size_t)(i0 + r)*1024 + j];
  __syncthreads();
  int i = threadIdx.x & 63, jj0 = (threadIdx.x >> 6)*16;
  float wc = w[c0 + i], bc = bias[c0 + i];
  bf16* yp = y3 + ((size_t)b*1024 + n0)*1024 + c0 + i;
  #pragma unroll
  for (int r = 0; r < 16; ++r){
    int n = n0 + jj0 + r;
    float v = t[jj0 + r][i];
    yp[(size_t)(jj0 + r)*1024] = f2b((v - mu[b*1024 + n])*rs[b*1024 + n]*wc + bc);
  }
}

// ================= 256x256 8-phase GEMM =================
// out(M,N) = A(M,K) * W(N,K)^T, bf16. 512 thr (8 waves 2Mx4N), BK=64.
// LDS: 4-slot ring (32KB: A[256][32]+B[256][32]), chunk-XOR swizzle both-sides.
// 2-K-tile unrolled loop; two base pointers per operand keep every ds_read
// offset immediate < 65536 (16-bit limit). vmcnt(4) at MH==1 phases only.
// EPI: 0 plain, 1 +bias+fast-gelu, 3 +bias+accumulate-into-out
#define PH(PA, PB, JO, MH, VM, STAGE_STMT)                                     \
  {                                                                            \
    if ((MH) == 0){                                                            \
      b[0] = dsr<(JO) +    0>(PB); b[1] = dsr<(JO) + 1024>(PB);                \
      b[2] = dsr<(JO) + 2048>(PB); b[3] = dsr<(JO) + 3072>(PB);                \
    }                                                                          \
    a[0] = dsr<(JO) + (MH)*4096u +    0>(PA);                                  \
    a[1] = dsr<(JO) + (MH)*4096u + 1024>(PA);                                  \
    a[2] = dsr<(JO) + (MH)*4096u + 2048>(PA);                                  \
    a[3] = dsr<(JO) + (MH)*4096u + 3072>(PA);                                  \
    STAGE_STMT;                                                                \
    if (VM) asm volatile("s_waitcnt vmcnt(4)" ::: "memory");                   \
    __builtin_amdgcn_s_barrier();                                              \
    asm volatile("s_waitcnt lgkmcnt(0)" ::: "memory");                         \
    __builtin_amdgcn_sched_barrier(0);                                         \
    __builtin_amdgcn_s_setprio(1);                                             \
    _Pragma("unroll")                                                          \
    for (int i_ = 0; i_ < 4; ++i_)                                             \
      _Pragma("unroll")                                                        \
      for (int n_ = 0; n_ < 4; ++n_)                                           \
        acc[(MH)*4 + i_][n_] = __builtin_amdgcn_mfma_f32_16x16x32_bf16(        \
            a[i_], b[n_], acc[(MH)*4 + i_][n_], 0, 0, 0);                      \
    __builtin_amdgcn_s_setprio(0);                                             \
    __builtin_amdgcn_s_barrier();                                              \
  }

#define STAGE_A(KB, SLOT)                                                      \
  { const char* g_ = Ag + (size_t)(KB)*2;                                      \
    gload16(g_,        smem + (SLOT)*32768 + t*16);                            \
    gload16(g_ + a128, smem + (SLOT)*32768 + 8192 + t*16); }
#define STAGE_B(KB, SLOT)                                                      \
  { const char* g_ = Wg + (size_t)(KB)*2;                                      \
    gload16(g_,        smem + (SLOT)*32768 + 16384 + t*16);                    \
    gload16(g_ + w128, smem + (SLOT)*32768 + 16384 + 8192 + t*16); }

template<int EPI>
__global__ void __launch_bounds__(512, 2) k_gemm8(const bf16* __restrict__ A,
                                                  const bf16* __restrict__ W,
                                                  bf16* __restrict__ out,
                                                  const float* __restrict__ bias,
                                                  int K, int lda, int ldw, int ldo,
                                                  int nbx){
  __shared__ __align__(16) char smem[131072];
  int nwg = gridDim.x;
  int cpx = nwg >> 3;
  int bid = blockIdx.x;
  int swz = (bid & 7)*cpx + (bid >> 3);
  int bx = swz % nbx, by = swz / nbx;
  int m0 = by*256, n0 = bx*256;
  int t = threadIdx.x;
  int lane = t & 63, wave = t >> 6;
  int wr = wave >> 2, wc = wave & 3;     // 2x4 waves; each owns 128x64
  int lr = lane & 15, lg = lane >> 4;
  unsigned cswz = (unsigned)((lg ^ ((lr >> 1) & 3))*16);
  int srow = t >> 2;
  int sg = (t & 3) ^ ((t >> 3) & 3);
  f32x4 acc[8][4] = {};
  bf16x8 a[4], b[4];
  int nt = K >> 6;                        // even (K = 1024 or 2048)

  // hoisted staging pointers (byte-level) and ds_read bases
  const char* Ag = (const char*)A + ((size_t)(m0 + srow)*lda + sg*8)*2;
  const char* Wg = (const char*)W + ((size_t)(n0 + srow)*ldw + sg*8)*2;
  const size_t a128 = (size_t)lda*256;    // +128 rows, bytes
  const size_t w128 = (size_t)ldw*256;
  // slots 0/1 base and slots 2/3 base (keeps ds_read immediates 16-bit)
  lds_cp pa0 = (lds_cp)(smem + (wr*128 + lr)*64 + cswz);
  lds_cp pb0 = (lds_cp)(smem + 16384 + (wc*64 + lr)*64 + cswz);
  lds_cp pa1 = pa0 + 65536;
  lds_cp pb1 = pb0 + 65536;

  // prologue: tile 0 -> slot0 (k 0..32), slot1 (k 32..64)
  STAGE_A(0, 0)  STAGE_B(0, 0)
  STAGE_A(32, 1) STAGE_B(32, 1)
  asm volatile("s_waitcnt vmcnt(4)" ::: "memory");
  __builtin_amdgcn_s_barrier();

  int nh = nt >> 1;
  for (int tp = 0; tp < nh; ++tp){
    int tt = tp*2;
    int kn  = (tt + 1)*64;                      // always valid (tt <= nt-2)
    int kn2 = (tt + 2 < nt) ? (tt + 2)*64 : 0;  // harmless reload on last iter
    // tile tt: read slots 0,1; stage tile tt+1 into slots 2,3
    PH(pa0, pb0, 0u,     0, 0, STAGE_A(kn, 2))
    PH(pa0, pb0, 0u,     1, 1, STAGE_B(kn, 2))
    PH(pa0, pb0, 32768u, 0, 0, STAGE_A(kn + 32, 3))
    PH(pa0, pb0, 32768u, 1, 1, STAGE_B(kn + 32, 3))
    // tile tt+1: read slots 2,3; stage tile tt+2 into slots 0,1
    PH(pa1, pb1, 0u,     0, 0, STAGE_A(kn2, 0))
    PH(pa1, pb1, 0u,     1, 1, STAGE_B(kn2, 0))
    PH(pa1, pb1, 32768u, 0, 0, STAGE_A(kn2 + 32, 1))
    PH(pa1, pb1, 32768u, 1, 1, STAGE_B(kn2 + 32, 1))
  }

  #pragma unroll
  for (int m = 0; m < 8; ++m){
    #pragma unroll
    for (int n = 0; n < 4; ++n){
      int col = n0 + wc*64 + n*16 + lr;
      #pragma unroll
      for (int j = 0; j < 4; ++j){
        int row = m0 + wr*128 + m*16 + lg*4 + j;
        size_t idx = (size_t)row*ldo + col;
        float v = acc[m][n][j];
        if (EPI >= 1) v += bias[col];
        if (EPI == 1) v = v / (1.f + __expf(-1.702f*v));   // fast gelu
        if (EPI == 3) v += b2f(out[idx]);
        out[idx] = f2b(v);
      }
    }
  }
}

// ---------------- chunk partial sums of w^2 (optionally * Pi) ----------------
template<bool WEIGHTED>
__global__ void k_chunksum(const bf16* __restrict__ Wb, const float* __restrict__ Pi,
                           float* __restrict__ S){
  int blk = blockIdx.x;
  int ch = blk & 15, h = (blk >> 4) & 7, b = blk >> 7;
  int dd = threadIdx.x;
  const bf16* wp = Wb + ((size_t)(b*1024) + ch*64)*1024 + h*128 + dd;
  float acc = 0.f;
  #pragma unroll 8
  for (int i = 0; i < 64; ++i){
    float w = b2f(wp[(size_t)i*1024]);
    float sq = w*w;
    if (WEIGHTED) sq *= Pi[(size_t)(b*8 + h)*1024 + ch*64 + i];
    acc += sq;
  }
  S[(size_t)blk*128 + dd] = acc;
}

// ---------------- stage A: running denom -> tmp(b,h,n) ----------------
__global__ void k_stageA(const bf16* __restrict__ Wb, const float* __restrict__ S1,
                         const float* __restrict__ temp, const float* __restrict__ dbias,
                         float* __restrict__ tmp){
  int blk = blockIdx.x;
  int ch = blk & 15, h = (blk >> 4) & 7, b = blk >> 7;
  int dd = threadIdx.x;
  const float* sp = S1 + (size_t)(b*8 + h)*16*128 + dd;
  float base = 0.f;
  for (int c = 0; c < ch; ++c) base += sp[(size_t)c*128];
  __shared__ float V[64][129];
  const bf16* wp = Wb + ((size_t)(b*1024) + ch*64)*1024 + h*128 + dd;
  float run = base;
  for (int i = 0; i < 64; ++i){
    float w = b2f(wp[(size_t)i*1024]);
    float sq = w*w;
    run += sq;
    V[i][dd] = sq / fmaxf(run, EPS16F);
  }
  __syncthreads();
  int tt = threadIdx.x;
  int n_loc = tt >> 1, half = tt & 1;
  float s = 0.f;
  for (int k = 0; k < 64; ++k) s += V[n_loc][half*64 + k];
  s += __shfl_xor(s, 1);
  if (half == 0){
    int n = ch*64 + n_loc;
    float db = dbias[h*1024 + n];
    tmp[(size_t)(b*8 + h)*1024 + n] = (s + 128.f*db)*temp[h];
  }
}

// ---------------- softmax over heads + inclusive scan of Pi over n ----------------
__global__ void k_softmax_scan(const float* __restrict__ tmp, float* __restrict__ Pi,
                               float* __restrict__ Pc){
  int bh = blockIdx.x; int b = bh >> 3, h = bh & 7;
  int t = threadIdx.x;
  const float* tp = tmp + (size_t)b*8*1024;
  float p[4];
  #pragma unroll
  for (int i = 0; i < 4; ++i){
    int n = t*4 + i;
    float v[8]; float mx = -1e30f;
    #pragma unroll
    for (int hh = 0; hh < 8; ++hh){ v[hh] = tp[hh*1024 + n]; mx = fmaxf(mx, v[hh]); }
    float Z = 0.f;
    #pragma unroll
    for (int hh = 0; hh < 8; ++hh) Z += expf(v[hh] - mx);
    p[i] = expf(v[h] - mx)/Z;
    Pi[(size_t)bh*1024 + n] = p[i];
  }
  float l0 = p[0], l1 = l0 + p[1], l2 = l1 + p[2], l3 = l2 + p[3];
  float ts = l3, sc = ts;
  int ln = t & 63, wv = t >> 6;
  #pragma unroll
  for (int d = 1; d < 64; d <<= 1){
    float o = __shfl_up(sc, d);
    if (ln >= d) sc += o;
  }
  __shared__ float wsum[4];
  if (ln == 63) wsum[wv] = sc;
  __syncthreads();
  float woff = 0.f;
  for (int w2 = 0; w2 < 4; ++w2) if (w2 < wv) woff += wsum[w2];
  float excl = woff + sc - ts;
  size_t o4 = (size_t)bh*1024 + t*4;
  Pc[o4]   = excl + l0;
  Pc[o4+1] = excl + l1;
  Pc[o4+2] = excl + l2;
  Pc[o4+3] = excl + l3;
}

// ---------------- stage C: dots -> y (B,N,O) bf16 ----------------
__global__ void k_stageC(const bf16* __restrict__ Wb, const float* __restrict__ S2,
                         const float* __restrict__ Pi, const float* __restrict__ Pc,
                         bf16* __restrict__ Y){
  int blk = blockIdx.x;
  int ch = blk & 15, h = (blk >> 4) & 7, b = blk >> 7;
  int dd = threadIdx.x;
  const float* sp = S2 + (size_t)(b*8 + h)*16*128 + dd;
  float base = 0.f;
  for (int c = 0; c < ch; ++c) base += sp[(size_t)c*128];
  const bf16* wp = Wb + ((size_t)(b*1024) + ch*64)*1024 + h*128 + dd;
  bf16* yp = Y + ((size_t)(b*1024) + ch*64)*1024 + h*128 + dd;
  const float* pip = Pi + (size_t)(b*8 + h)*1024 + ch*64;
  const float* pcp = Pc + (size_t)(b*8 + h)*1024 + ch*64;
  float run = base;
  for (int i = 0; i < 64; ++i){
    float w = b2f(wp[(size_t)i*1024]);
    float sq = w*w;
    float pi = pip[i];
    run += sq*pi;
    float dots = run / (pcp[i] + EPS16F);
    float at = 1.0f/(1.0f + dots);
    yp[(size_t)i*1024] = f2b(-(w*pi)*at);
  }
}

// ---------------- residual 1: x1(B,N,C) = xT + g1 * a ----------------
__global__ void k_resid1(const float* __restrict__ x, const bf16* __restrict__ Ab,
                         const float* __restrict__ g1, float* __restrict__ x1){
  int b = blockIdx.z, c0 = blockIdx.y*64, n0 = blockIdx.x*64;
  __shared__ float t[64][65];
  int j = threadIdx.x & 63, i0 = (threadIdx.x >> 6)*16;
  const float* xp = x + ((size_t)b*1024 + c0)*1024 + n0;
  #pragma unroll
  for (int r = 0; r < 16; ++r)
    t[j][i0 + r] = xp[(size_t)(i0 + r)*1024 + j];
  __syncthreads();
  int i = threadIdx.x & 63, jj0 = (threadIdx.x >> 6)*16;
  float g = g1[c0 + i];
  #pragma unroll
  for (int r = 0; r < 16; ++r){
    size_t off = ((size_t)b*1024 + n0 + jj0 + r)*1024 + c0 + i;
    x1[off] = t[jj0 + r][i] + g*b2f(Ab[off]);
  }
}

// ---------------- LN2 fused (row-contig) -> Y4 bf16 ----------------
__global__ void k_ln2(const float* __restrict__ x1, const float* __restrict__ w,
                      const float* __restrict__ bias, bf16* __restrict__ y4){
  int row = blockIdx.x, t = threadIdx.x;
  const float4* rp = (const float4*)(x1 + (size_t)row*1024);
  float4 v = rp[t];
  float s = v.x + v.y + v.z + v.w;
  float q = v.x*v.x + v.y*v.y + v.z*v.z + v.w*v.w;
  #pragma unroll
  for (int d = 32; d >= 1; d >>= 1){ s += __shfl_xor(s, d); q += __shfl_xor(q, d); }
  __shared__ float ss[4], qq[4];
  int wv = t >> 6, ln = t & 63;
  if (ln == 0){ ss[wv] = s; qq[wv] = q; }
  __syncthreads();
  s = ss[0] + ss[1] + ss[2] + ss[3];
  q = qq[0] + qq[1] + qq[2] + qq[3];
  float m = s*(1.f/1024.f);
  float var = q*(1.f/1024.f) - m*m;
  float r = rsqrtf(var + 1e-5f);
  int c = t*4;
  ushort4 pk = make_ushort4(
      f2bu((v.x - m)*r*w[c]   + bias[c]),
      f2bu((v.y - m)*r*w[c+1] + bias[c+1]),
      f2bu((v.z - m)*r*w[c+2] + bias[c+2]),
      f2bu((v.w - m)*r*w[c+3] + bias[c+3]));
  *reinterpret_cast<ushort4*>(y4 + (size_t)row*1024 + c) = pk;
}

// ---------------- residual 2 + transpose: out(B,C,N) = x1 + g2*m ----------------
__global__ void k_resid2(const float* __restrict__ x1, const bf16* __restrict__ Mb,
                         const float* __restrict__ g2, float* __restrict__ out){
  int b = blockIdx.z, c0 = blockIdx.y*64, n0 = blockIdx.x*64;
  __shared__ float t[64][65];
  int i = threadIdx.x & 63, j0 = (threadIdx.x >> 6)*16;
  float g = g2[c0 + i];
  #pragma unroll
  for (int r = 0; r < 16; ++r){
    size_t off = ((size_t)b*1024 + n0 + j0 + r)*1024 + c0 + i;
    t[i][j0 + r] = x1[off] + g*b2f(Mb[off]);
  }
  __syncthreads();
  int j = threadIdx.x & 63, i0 = (threadIdx.x >> 6)*16;
  #pragma unroll
  for (int r = 0; r < 16; ++r)
    out[((size_t)b*1024 + c0 + i0 + r)*1024 + n0 + j] = t[i0 + r][j];
}

extern "C" void kernel_launch(void* const* d_in, const int* in_sizes, int n_in,
                              void* d_out, int out_size, void* d_ws, size_t ws_size,
                              hipStream_t stream){
  (void)in_sizes; (void)n_in; (void)out_size; (void)ws_size;
  const float* x      = (const float*)d_in[0];
  const float* ln1_w  = (const float*)d_in[1];
  const float* ln1_b  = (const float*)d_in[2];
  const float* Wattn  = (const float*)d_in[3];
  const float* Wproj  = (const float*)d_in[4];
  const float* temp   = (const float*)d_in[5];
  const float* dbias  = (const float*)d_in[6];
  const float* ln2_w  = (const float*)d_in[7];
  const float* ln2_b  = (const float*)d_in[8];
  const float* W1     = (const float*)d_in[9];
  const float* b1     = (const float*)d_in[10];
  const float* W2     = (const float*)d_in[11];
  const float* b2     = (const float*)d_in[12];
  const float* g1     = (const float*)d_in[13];
  const float* g2     = (const float*)d_in[14];
  float* out = (float*)d_out;

  size_t off = 0;
  char* wsb = (char*)d_ws;
  auto alloc = [&](size_t bytes)->char*{
    char* p = wsb + off; off += (bytes + 255) & ~(size_t)255; return p;
  };
  bf16*  Y3  = (bf16*)alloc((size_t)16384*1024*2);   // also Y4 (LN2 out)
  bf16*  Wb  = (bf16*)alloc((size_t)16384*1024*2);   // also Ab; also H-half lo
  bf16*  Yb  = (bf16*)alloc((size_t)16384*1024*2);   // TSSA y; also H-half hi
  bf16*  Mb  = (bf16*)alloc((size_t)16384*1024*2);   // MLP-down accum (bf16)
  float* x1  = (float*)alloc((size_t)16384*1024*4);
  bf16*  WAb = (bf16*)alloc((size_t)1024*1024*2);
  bf16*  WPb = (bf16*)alloc((size_t)1024*1024*2);
  bf16*  W1b = (bf16*)alloc((size_t)4096*1024*2);
  bf16*  W2b = (bf16*)alloc((size_t)4096*1024*2);
  float* mu  = (float*)alloc((size_t)16384*4);
  float* rs  = (float*)alloc((size_t)16384*4);
  float* S   = (float*)alloc((size_t)2048*128*4);
  float* tmp = (float*)alloc((size_t)16*8*1024*4);
  float* Pi  = (float*)alloc((size_t)16*8*1024*4);
  float* Pc  = (float*)alloc((size_t)16*8*1024*4);
  float* Ps  = (float*)alloc((size_t)16*64*1024*4);
  float* Pq  = (float*)alloc((size_t)16*64*1024*4);

  dim3 b256(256), b128(128), b512(512);

  // weights -> bf16
  k_f2b<<<dim3((1024*1024/4 + 255)/256), b256, 0, stream>>>(Wattn, WAb, 1024*1024);
  k_f2b<<<dim3((1024*1024/4 + 255)/256), b256, 0, stream>>>(Wproj, WPb, 1024*1024);
  k_f2b<<<dim3((4096*1024/4 + 255)/256), b256, 0, stream>>>(W1, W1b, 4096*1024);
  k_f2b<<<dim3((4096*1024/4 + 255)/256), b256, 0, stream>>>(W2, W2b, 4096*1024);

  // LN1 stats (two-phase, coalesced)
  k_ln1_part<<<dim3(64, 16), b256, 0, stream>>>(x, Ps, Pq);
  k_ln1_finish<<<dim3(4, 16), b256, 0, stream>>>(Ps, Pq, mu, rs);
  k_ln1_apply<<<dim3(16, 16, 16), b256, 0, stream>>>(x, mu, rs, ln1_w, ln1_b, Y3);

  // c_attn: (16384,1024,1024) -> 64x4 = 256 blocks
  k_gemm8<0><<<dim3(256), b512, 0, stream>>>(Y3, WAb, Wb, nullptr,
                                             1024, 1024, 1024, 1024, 4);

  // TSSA elementwise chain
  k_chunksum<false><<<dim3(2048), b128, 0, stream>>>(Wb, nullptr, S);
  k_stageA<<<dim3(2048), b128, 0, stream>>>(Wb, S, temp, dbias, tmp);
  k_softmax_scan<<<dim3(128), b256, 0, stream>>>(tmp, Pi, Pc);
  k_chunksum<true><<<dim3(2048), b128, 0, stream>>>(Wb, Pi, S);
  k_stageC<<<dim3(2048), b128, 0, stream>>>(Wb, S, Pi, Pc, Yb);

  // c_proj (writes into Wb slab, now free)
  bf16* Ab = Wb;
  k_gemm8<0><<<dim3(256), b512, 0, stream>>>(Yb, WPb, Ab, nullptr,
                                             1024, 1024, 1024, 1024, 4);

  // residual 1 (x is (B,C,N); x1 is (B,N,C) fp32)
  k_resid1<<<dim3(16, 16, 16), b256, 0, stream>>>(x, Ab, g1, x1);

  // LN2 -> Y4 (reuse Y3 slab)
  k_ln2<<<dim3(16384), b256, 0, stream>>>(x1, ln2_w, ln2_b, Y3);

  // MLP chunked over hidden dim F (2 x 2048); H-half overlays dead [Wb|Yb].
  bf16* Hb = Wb;
  for (int f = 0; f < 2; ++f){
    // up: (16384,2048,1024) -> 64x8 = 512 blocks
    k_gemm8<1><<<dim3(512), b512, 0, stream>>>(Y3, W1b + (size_t)f*2048*1024, Hb,
                                               b1 + f*2048, 1024, 1024, 1024, 2048, 8);
    // down: (16384,1024,2048) -> 256 blocks; f=1 accumulates + bias
    if (f == 0)
      k_gemm8<0><<<dim3(256), b512, 0, stream>>>(Hb, W2b + f*2048, Mb, nullptr,
                                                 2048, 2048, 4096, 1024, 4);
    else
      k_gemm8<3><<<dim3(256), b512, 0, stream>>>(Hb, W2b + f*2048, Mb, b2,
                                                 2048, 2048, 4096, 1024, 4);
  }

  // residual 2 + transpose to (B,C,H,W)
  k_resid2<<<dim3(16, 16, 16), b256, 0, stream>>>(x1, Mb, g2, out);
}

// Round 8
// 580.996 us; speedup vs baseline: 1.7358x; 1.0091x over previous
//
#include <hip/hip_runtime.h>
#include <hip/hip_bf16.h>
#include <math.h>

using bf16 = __hip_bfloat16;
typedef __bf16 bf16x8 __attribute__((ext_vector_type(8)));
typedef float f32x4 __attribute__((ext_vector_type(4)));

#define EPS16F 0.0009765625f

__device__ __forceinline__ float b2f(bf16 v){ return __bfloat162float(v); }
__device__ __forceinline__ bf16  f2b(float f){ return __float2bfloat16(f); }
__device__ __forceinline__ unsigned short f2bu(float f){
  bf16 h = __float2bfloat16(f); return __builtin_bit_cast(unsigned short, h);
}

__device__ __forceinline__ void gload16(const void* g, void* l){
  __builtin_amdgcn_global_load_lds((const __attribute__((address_space(1))) void*)g,
                                   (__attribute__((address_space(3))) void*)l, 16, 0, 0);
}

typedef const __attribute__((address_space(3))) char* lds_cp;

// LDS vector read with compile-time immediate offset (16-bit limit)
template<unsigned OFF>
__device__ __forceinline__ bf16x8 dsr(lds_cp p){
  static_assert(OFF < 65536u, "ds_read offset is 16-bit");
  bf16x8 d;
  asm volatile("ds_read_b128 %0, %1 offset:%c2"
               : "=v"(d) : "v"(p), "i"(OFF));
  return d;
}

__device__ __forceinline__ f32x4 mfma(bf16x8 av, bf16x8 bv, f32x4 c){
  return __builtin_amdgcn_mfma_f32_16x16x32_bf16(av, bv, c, 0, 0, 0);
}

// ---------------- fp32 -> bf16 convert ----------------
__global__ void k_f2b(const float* __restrict__ in, bf16* __restrict__ out, int n){
  int i = (blockIdx.x*blockDim.x + threadIdx.x)*4;
  if (i + 3 < n){
    float4 v = *(const float4*)(in + i);
    ushort4 pk = make_ushort4(f2bu(v.x), f2bu(v.y), f2bu(v.z), f2bu(v.w));
    *reinterpret_cast<ushort4*>(out + i) = pk;
  } else {
    for (; i < n; ++i) out[i] = f2b(in[i]);
  }
}

// ---------------- LN1 stats phase 1 ----------------
__global__ void __launch_bounds__(256) k_ln1_part(const float* __restrict__ x,
                                                  float* __restrict__ Ps,
                                                  float* __restrict__ Pq){
  int chunk = blockIdx.x, b = blockIdx.y;
  int t = threadIdx.x;
  const float4* xp = (const float4*)(x + ((size_t)b*1024 + chunk*16)*1024) + t;
  float4 s = {0.f,0.f,0.f,0.f}, q = {0.f,0.f,0.f,0.f};
  #pragma unroll
  for (int c = 0; c < 16; ++c){
    float4 v = xp[c*256];
    s.x += v.x; s.y += v.y; s.z += v.z; s.w += v.w;
    q.x += v.x*v.x; q.y += v.y*v.y; q.z += v.z*v.z; q.w += v.w*v.w;
  }
  size_t o = ((size_t)(b*64 + chunk))*256 + t;
  ((float4*)Ps)[o] = s;
  ((float4*)Pq)[o] = q;
}

// ---------------- LN1 stats phase 2 ----------------
__global__ void __launch_bounds__(256) k_ln1_finish(const float* __restrict__ Ps,
                                                    const float* __restrict__ Pq,
                                                    float* __restrict__ mu,
                                                    float* __restrict__ rs){
  int nb = blockIdx.x, b = blockIdx.y;
  int n = nb*256 + threadIdx.x;
  const float* ps = Ps + (size_t)b*64*1024 + n;
  const float* pq = Pq + (size_t)b*64*1024 + n;
  float S = 0.f, Q = 0.f;
  #pragma unroll 8
  for (int c = 0; c < 64; ++c){ S += ps[(size_t)c*1024]; Q += pq[(size_t)c*1024]; }
  float m = S*(1.f/1024.f);
  float var = Q*(1.f/1024.f) - m*m;
  mu[b*1024 + n] = m;
  rs[b*1024 + n] = rsqrtf(var + 1e-5f);
}

// ---------------- LN1 apply + transpose ----------------
__global__ void k_ln1_apply(const float* __restrict__ x, const float* __restrict__ mu,
                            const float* __restrict__ rs, const float* __restrict__ w,
                            const float* __restrict__ bias, bf16* __restrict__ y3){
  int b = blockIdx.z, c0 = blockIdx.y*64, n0 = blockIdx.x*64;
  __shared__ float t[64][65];
  int j = threadIdx.x & 63, i0 = (threadIdx.x >> 6)*16;
  const float* xp = x + ((size_t)b*1024 + c0)*1024 + n0;
  #pragma unroll
  for (int r = 0; r < 16; ++r)
    t[j][i0 + r] = xp[(size_t)(i0 + r)*1024 + j];
  __syncthreads();
  int i = threadIdx.x & 63, jj0 = (threadIdx.x >> 6)*16;
  float wc = w[c0 + i], bc = bias[c0 + i];
  bf16* yp = y3 + ((size_t)b*1024 + n0)*1024 + c0 + i;
  #pragma unroll
  for (int r = 0; r < 16; ++r){
    int n = n0 + jj0 + r;
    float v = t[jj0 + r][i];
    yp[(size_t)(jj0 + r)*1024] = f2b((v - mu[b*1024 + n])*rs[b*1024 + n]*wc + bc);
  }
}

// ================= 256x256 reg-pipelined GEMM =================
// out(M,N) = A(M,K)*W(N,K)^T bf16. 512 thr (8 waves 2Mx4N). chunk = 32 k.
// 4-slot LDS ring (32KB: A[256][32]+B[256][32]), chunk-XOR swizzle both-sides.
// Per chunk: issue 12 ds_read for chunk c+1 (other reg buf), stage chunk c+3,
// lgkmcnt(12) [waits only OLD reads], 32 MFMA (overlaps new reads+staging),
// vmcnt(4) [chunk c+2 landed], ONE barrier. Unrolled x4 (static slots/bufs).
// EPI: 0 plain, 1 +bias+fast-gelu, 3 +bias+accumulate-into-out
#define RD(NXA, NXB, PA, PB, IMM)                                              \
  NXA[0] = dsr<(IMM)+    0>(PA); NXA[1] = dsr<(IMM)+ 1024>(PA);                \
  NXA[2] = dsr<(IMM)+ 2048>(PA); NXA[3] = dsr<(IMM)+ 3072>(PA);                \
  NXA[4] = dsr<(IMM)+ 4096>(PA); NXA[5] = dsr<(IMM)+ 5120>(PA);                \
  NXA[6] = dsr<(IMM)+ 6144>(PA); NXA[7] = dsr<(IMM)+ 7168>(PA);                \
  NXB[0] = dsr<(IMM)+    0>(PB); NXB[1] = dsr<(IMM)+ 1024>(PB);                \
  NXB[2] = dsr<(IMM)+ 2048>(PB); NXB[3] = dsr<(IMM)+ 3072>(PB);

#define STAGE_A(KB, SLOT)                                                      \
  { const char* g_ = Ag + (size_t)(KB)*2;                                      \
    gload16(g_,        smem + (SLOT)*32768 + t*16);                            \
    gload16(g_ + a128, smem + (SLOT)*32768 + 8192 + t*16); }
#define STAGE_B(KB, SLOT)                                                      \
  { const char* g_ = Wg + (size_t)(KB)*2;                                      \
    gload16(g_,        smem + (SLOT)*32768 + 16384 + t*16);                    \
    gload16(g_ + w128, smem + (SLOT)*32768 + 16384 + 8192 + t*16); }

#define CHUNK(C_, NXA, NXB, CA, CB, PA, PB, RIMM, SSL)                         \
  {                                                                            \
    bool rd = (C_) + 1 < NC;                                                   \
    bool st = (C_) + 3 < NC;                                                   \
    if (rd){ RD(NXA, NXB, PA, PB, RIMM) }                                      \
    if (st){ int kb_ = ((C_) + 3)*32;                                          \
      STAGE_A(kb_, SSL) STAGE_B(kb_, SSL) }                                    \
    if (rd) asm volatile("s_waitcnt lgkmcnt(12)" ::: "memory");                \
    else    asm volatile("s_waitcnt lgkmcnt(0)"  ::: "memory");                \
    __builtin_amdgcn_sched_barrier(0);                                         \
    __builtin_amdgcn_s_setprio(1);                                             \
    _Pragma("unroll")                                                          \
    for (int i_ = 0; i_ < 4; ++i_)                                             \
      _Pragma("unroll")                                                        \
      for (int n_ = 0; n_ < 4; ++n_){                                          \
        acc[i_][n_]     = mfma(CA[i_],     CB[n_], acc[i_][n_]);               \
        acc[4 + i_][n_] = mfma(CA[4 + i_], CB[n_], acc[4 + i_][n_]);           \
      }                                                                        \
    __builtin_amdgcn_s_setprio(0);                                             \
    if (st) asm volatile("s_waitcnt vmcnt(4)" ::: "memory");                   \
    else    asm volatile("s_waitcnt vmcnt(0)" ::: "memory");                   \
    __builtin_amdgcn_s_barrier();                                              \
  }

template<int EPI>
__global__ void __launch_bounds__(512, 2) k_gemm8(const bf16* __restrict__ A,
                                                  const bf16* __restrict__ W,
                                                  bf16* __restrict__ out,
                                                  const float* __restrict__ bias,
                                                  int K, int lda, int ldw, int ldo,
                                                  int nbx){
  __shared__ __align__(16) char smem[131072];
  int nwg = gridDim.x;
  int cpx = nwg >> 3;
  int bid = blockIdx.x;
  int swz = (bid & 7)*cpx + (bid >> 3);
  int bx = swz % nbx, by = swz / nbx;
  int m0 = by*256, n0 = bx*256;
  int t = threadIdx.x;
  int lane = t & 63, wave = t >> 6;
  int wr = wave >> 2, wc = wave & 3;     // 2x4 waves; each owns 128x64
  int lr = lane & 15, lg = lane >> 4;
  unsigned cswz = (unsigned)((lg ^ ((lr >> 1) & 3))*16);
  int srow = t >> 2;
  int sg = (t & 3) ^ ((t >> 3) & 3);
  f32x4 acc[8][4] = {};
  bf16x8 aE[8], bE[4], aO[8], bO[4];
  int NC = K >> 5;                        // chunks of 32 k; multiple of 4 here

  const char* Ag = (const char*)A + ((size_t)(m0 + srow)*lda + sg*8)*2;
  const char* Wg = (const char*)W + ((size_t)(n0 + srow)*ldw + sg*8)*2;
  const size_t a128 = (size_t)lda*256;    // +128 rows, bytes
  const size_t w128 = (size_t)ldw*256;
  // slot bases: pa0/pb0 for slots 0,1 (imm 0/32768); pa1/pb1 for slots 2,3
  lds_cp pa0 = (lds_cp)(smem + (wr*128 + lr)*64 + cswz);
  lds_cp pb0 = (lds_cp)(smem + 16384 + (wc*64 + lr)*64 + cswz);
  lds_cp pa1 = pa0 + 65536;
  lds_cp pb1 = pb0 + 65536;

  // prologue: stage chunks 0,1,2 -> slots 0,1,2
  STAGE_A(0, 0)  STAGE_B(0, 0)
  STAGE_A(32, 1) STAGE_B(32, 1)
  STAGE_A(64, 2) STAGE_B(64, 2)
  asm volatile("s_waitcnt vmcnt(4)" ::: "memory");   // chunks 0,1 landed
  __builtin_amdgcn_s_barrier();
  RD(aE, bE, pa0, pb0, 0u)                            // chunk 0 -> E bufs

  int ng = NC >> 2;
  for (int g = 0; g < ng; ++g){
    int c0 = g*4;
    CHUNK(c0 + 0, aO, bO, aE, bE, pa0, pb0, 32768u, 3)  // rd slot1, st slot3
    CHUNK(c0 + 1, aE, bE, aO, bO, pa1, pb1, 0u,     0)  // rd slot2, st slot0
    CHUNK(c0 + 2, aO, bO, aE, bE, pa1, pb1, 32768u, 1)  // rd slot3, st slot1
    CHUNK(c0 + 3, aE, bE, aO, bO, pa0, pb0, 0u,     2)  // rd slot0, st slot2
  }

  #pragma unroll
  for (int m = 0; m < 8; ++m){
    #pragma unroll
    for (int n = 0; n < 4; ++n){
      int col = n0 + wc*64 + n*16 + lr;
      #pragma unroll
      for (int j = 0; j < 4; ++j){
        int row = m0 + wr*128 + m*16 + lg*4 + j;
        size_t idx = (size_t)row*ldo + col;
        float v = acc[m][n][j];
        if (EPI >= 1) v += bias[col];
        if (EPI == 1) v = v / (1.f + __expf(-1.702f*v));   // fast gelu
        if (EPI == 3) v += b2f(out[idx]);
        out[idx] = f2b(v);
      }
    }
  }
}

// ---------------- chunk partial sums of w^2 (optionally * Pi) ----------------
template<bool WEIGHTED>
__global__ void k_chunksum(const bf16* __restrict__ Wb, const float* __restrict__ Pi,
                           float* __restrict__ S){
  int blk = blockIdx.x;
  int ch = blk & 15, h = (blk >> 4) & 7, b = blk >> 7;
  int dd = threadIdx.x;
  const bf16* wp = Wb + ((size_t)(b*1024) + ch*64)*1024 + h*128 + dd;
  float acc = 0.f;
  #pragma unroll 8
  for (int i = 0; i < 64; ++i){
    float w = b2f(wp[(size_t)i*1024]);
    float sq = w*w;
    if (WEIGHTED) sq *= Pi[(size_t)(b*8 + h)*1024 + ch*64 + i];
    acc += sq;
  }
  S[(size_t)blk*128 + dd] = acc;
}

// ---------------- stage A: running denom -> tmp(b,h,n) ----------------
__global__ void k_stageA(const bf16* __restrict__ Wb, const float* __restrict__ S1,
                         const float* __restrict__ temp, const float* __restrict__ dbias,
                         float* __restrict__ tmp){
  int blk = blockIdx.x;
  int ch = blk & 15, h = (blk >> 4) & 7, b = blk >> 7;
  int dd = threadIdx.x;
  const float* sp = S1 + (size_t)(b*8 + h)*16*128 + dd;
  float base = 0.f;
  for (int c = 0; c < ch; ++c) base += sp[(size_t)c*128];
  __shared__ float V[64][129];
  const bf16* wp = Wb + ((size_t)(b*1024) + ch*64)*1024 + h*128 + dd;
  float run = base;
  for (int i = 0; i < 64; ++i){
    float w = b2f(wp[(size_t)i*1024]);
    float sq = w*w;
    run += sq;
    V[i][dd] = sq / fmaxf(run, EPS16F);
  }
  __syncthreads();
  int tt = threadIdx.x;
  int n_loc = tt >> 1, half = tt & 1;
  float s = 0.f;
  for (int k = 0; k < 64; ++k) s += V[n_loc][half*64 + k];
  s += __shfl_xor(s, 1);
  if (half == 0){
    int n = ch*64 + n_loc;
    float db = dbias[h*1024 + n];
    tmp[(size_t)(b*8 + h)*1024 + n] = (s + 128.f*db)*temp[h];
  }
}

// ---------------- softmax over heads + inclusive scan of Pi over n ----------------
__global__ void k_softmax_scan(const float* __restrict__ tmp, float* __restrict__ Pi,
                               float* __restrict__ Pc){
  int bh = blockIdx.x; int b = bh >> 3, h = bh & 7;
  int t = threadIdx.x;
  const float* tp = tmp + (size_t)b*8*1024;
  float p[4];
  #pragma unroll
  for (int i = 0; i < 4; ++i){
    int n = t*4 + i;
    float v[8]; float mx = -1e30f;
    #pragma unroll
    for (int hh = 0; hh < 8; ++hh){ v[hh] = tp[hh*1024 + n]; mx = fmaxf(mx, v[hh]); }
    float Z = 0.f;
    #pragma unroll
    for (int hh = 0; hh < 8; ++hh) Z += expf(v[hh] - mx);
    p[i] = expf(v[h] - mx)/Z;
    Pi[(size_t)bh*1024 + n] = p[i];
  }
  float l0 = p[0], l1 = l0 + p[1], l2 = l1 + p[2], l3 = l2 + p[3];
  float ts = l3, sc = ts;
  int ln = t & 63, wv = t >> 6;
  #pragma unroll
  for (int d = 1; d < 64; d <<= 1){
    float o = __shfl_up(sc, d);
    if (ln >= d) sc += o;
  }
  __shared__ float wsum[4];
  if (ln == 63) wsum[wv] = sc;
  __syncthreads();
  float woff = 0.f;
  for (int w2 = 0; w2 < 4; ++w2) if (w2 < wv) woff += wsum[w2];
  float excl = woff + sc - ts;
  size_t o4 = (size_t)bh*1024 + t*4;
  Pc[o4]   = excl + l0;
  Pc[o4+1] = excl + l1;
  Pc[o4+2] = excl + l2;
  Pc[o4+3] = excl + l3;
}

// ---------------- stage C: dots -> y (B,N,O) bf16 ----------------
__global__ void k_stageC(const bf16* __restrict__ Wb, const float* __restrict__ S2,
                         const float* __restrict__ Pi, const float* __restrict__ Pc,
                         bf16* __restrict__ Y){
  int blk = blockIdx.x;
  int ch = blk & 15, h = (blk >> 4) & 7, b = blk >> 7;
  int dd = threadIdx.x;
  const float* sp = S2 + (size_t)(b*8 + h)*16*128 + dd;
  float base = 0.f;
  for (int c = 0; c < ch; ++c) base += sp[(size_t)c*128];
  const bf16* wp = Wb + ((size_t)(b*1024) + ch*64)*1024 + h*128 + dd;
  bf16* yp = Y + ((size_t)(b*1024) + ch*64)*1024 + h*128 + dd;
  const float* pip = Pi + (size_t)(b*8 + h)*1024 + ch*64;
  const float* pcp = Pc + (size_t)(b*8 + h)*1024 + ch*64;
  float run = base;
  for (int i = 0; i < 64; ++i){
    float w = b2f(wp[(size_t)i*1024]);
    float sq = w*w;
    float pi = pip[i];
    run += sq*pi;
    float dots = run / (pcp[i] + EPS16F);
    float at = 1.0f/(1.0f + dots);
    yp[(size_t)i*1024] = f2b(-(w*pi)*at);
  }
}

// ---------------- residual 1: x1(B,N,C) = xT + g1 * a ----------------
__global__ void k_resid1(const float* __restrict__ x, const bf16* __restrict__ Ab,
                         const float* __restrict__ g1, float* __restrict__ x1){
  int b = blockIdx.z, c0 = blockIdx.y*64, n0 = blockIdx.x*64;
  __shared__ float t[64][65];
  int j = threadIdx.x & 63, i0 = (threadIdx.x >> 6)*16;
  const float* xp = x + ((size_t)b*1024 + c0)*1024 + n0;
  #pragma unroll
  for (int r = 0; r < 16; ++r)
    t[j][i0 + r] = xp[(size_t)(i0 + r)*1024 + j];
  __syncthreads();
  int i = threadIdx.x & 63, jj0 = (threadIdx.x >> 6)*16;
  float g = g1[c0 + i];
  #pragma unroll
  for (int r = 0; r < 16; ++r){
    size_t off = ((size_t)b*1024 + n0 + jj0 + r)*1024 + c0 + i;
    x1[off] = t[jj0 + r][i] + g*b2f(Ab[off]);
  }
}

// ---------------- LN2 fused (row-contig) -> Y4 bf16 ----------------
__global__ void k_ln2(const float* __restrict__ x1, const float* __restrict__ w,
                      const float* __restrict__ bias, bf16* __restrict__ y4){
  int row = blockIdx.x, t = threadIdx.x;
  const float4* rp = (const float4*)(x1 + (size_t)row*1024);
  float4 v = rp[t];
  float s = v.x + v.y + v.z + v.w;
  float q = v.x*v.x + v.y*v.y + v.z*v.z + v.w*v.w;
  #pragma unroll
  for (int d = 32; d >= 1; d >>= 1){ s += __shfl_xor(s, d); q += __shfl_xor(q, d); }
  __shared__ float ss[4], qq[4];
  int wv = t >> 6, ln = t & 63;
  if (ln == 0){ ss[wv] = s; qq[wv] = q; }
  __syncthreads();
  s = ss[0] + ss[1] + ss[2] + ss[3];
  q = qq[0] + qq[1] + qq[2] + qq[3];
  float m = s*(1.f/1024.f);
  float var = q*(1.f/1024.f) - m*m;
  float r = rsqrtf(var + 1e-5f);
  int c = t*4;
  ushort4 pk = make_ushort4(
      f2bu((v.x - m)*r*w[c]   + bias[c]),
      f2bu((v.y - m)*r*w[c+1] + bias[c+1]),
      f2bu((v.z - m)*r*w[c+2] + bias[c+2]),
      f2bu((v.w - m)*r*w[c+3] + bias[c+3]));
  *reinterpret_cast<ushort4*>(y4 + (size_t)row*1024 + c) = pk;
}

// ---------------- residual 2 + transpose: out(B,C,N) = x1 + g2*m ----------------
__global__ void k_resid2(const float* __restrict__ x1, const bf16* __restrict__ Mb,
                         const float* __restrict__ g2, float* __restrict__ out){
  int b = blockIdx.z, c0 = blockIdx.y*64, n0 = blockIdx.x*64;
  __shared__ float t[64][65];
  int i = threadIdx.x & 63, j0 = (threadIdx.x >> 6)*16;
  float g = g2[c0 + i];
  #pragma unroll
  for (int r = 0; r < 16; ++r){
    size_t off = ((size_t)b*1024 + n0 + j0 + r)*1024 + c0 + i;
    t[i][j0 + r] = x1[off] + g*b2f(Mb[off]);
  }
  __syncthreads();
  int j = threadIdx.x & 63, i0 = (threadIdx.x >> 6)*16;
  #pragma unroll
  for (int r = 0; r < 16; ++r)
    out[((size_t)b*1024 + c0 + i0 + r)*1024 + n0 + j] = t[i0 + r][j];
}

extern "C" void kernel_launch(void* const* d_in, const int* in_sizes, int n_in,
                              void* d_out, int out_size, void* d_ws, size_t ws_size,
                              hipStream_t stream){
  (void)in_sizes; (void)n_in; (void)out_size; (void)ws_size;
  const float* x      = (const float*)d_in[0];
  const float* ln1_w  = (const float*)d_in[1];
  const float* ln1_b  = (const float*)d_in[2];
  const float* Wattn  = (const float*)d_in[3];
  const float* Wproj  = (const float*)d_in[4];
  const float* temp   = (const float*)d_in[5];
  const float* dbias  = (const float*)d_in[6];
  const float* ln2_w  = (const float*)d_in[7];
  const float* ln2_b  = (const float*)d_in[8];
  const float* W1     = (const float*)d_in[9];
  const float* b1     = (const float*)d_in[10];
  const float* W2     = (const float*)d_in[11];
  const float* b2     = (const float*)d_in[12];
  const float* g1     = (const float*)d_in[13];
  const float* g2     = (const float*)d_in[14];
  float* out = (float*)d_out;

  size_t off = 0;
  char* wsb = (char*)d_ws;
  auto alloc = [&](size_t bytes)->char*{
    char* p = wsb + off; off += (bytes + 255) & ~(size_t)255; return p;
  };
  bf16*  Y3  = (bf16*)alloc((size_t)16384*1024*2);   // also Y4 (LN2 out)
  bf16*  Wb  = (bf16*)alloc((size_t)16384*1024*2);   // also Ab; also H-half lo
  bf16*  Yb  = (bf16*)alloc((size_t)16384*1024*2);   // TSSA y; also H-half hi
  bf16*  Mb  = (bf16*)alloc((size_t)16384*1024*2);   // MLP-down accum (bf16)
  float* x1  = (float*)alloc((size_t)16384*1024*4);
  bf16*  WAb = (bf16*)alloc((size_t)1024*1024*2);
  bf16*  WPb = (bf16*)alloc((size_t)1024*1024*2);
  bf16*  W1b = (bf16*)alloc((size_t)4096*1024*2);
  bf16*  W2b = (bf16*)alloc((size_t)4096*1024*2);
  float* mu  = (float*)alloc((size_t)16384*4);
  float* rs  = (float*)alloc((size_t)16384*4);
  float* S   = (float*)alloc((size_t)2048*128*4);
  float* tmp = (float*)alloc((size_t)16*8*1024*4);
  float* Pi  = (float*)alloc((size_t)16*8*1024*4);
  float* Pc  = (float*)alloc((size_t)16*8*1024*4);
  float* Ps  = (float*)alloc((size_t)16*64*1024*4);
  float* Pq  = (float*)alloc((size_t)16*64*1024*4);

  dim3 b256(256), b128(128), b512(512);

  // weights -> bf16
  k_f2b<<<dim3((1024*1024/4 + 255)/256), b256, 0, stream>>>(Wattn, WAb, 1024*1024);
  k_f2b<<<dim3((1024*1024/4 + 255)/256), b256, 0, stream>>>(Wproj, WPb, 1024*1024);
  k_f2b<<<dim3((4096*1024/4 + 255)/256), b256, 0, stream>>>(W1, W1b, 4096*1024);
  k_f2b<<<dim3((4096*1024/4 + 255)/256), b256, 0, stream>>>(W2, W2b, 4096*1024);

  // LN1 stats (two-phase, coalesced)
  k_ln1_part<<<dim3(64, 16), b256, 0, stream>>>(x, Ps, Pq);
  k_ln1_finish<<<dim3(4, 16), b256, 0, stream>>>(Ps, Pq, mu, rs);
  k_ln1_apply<<<dim3(16, 16, 16), b256, 0, stream>>>(x, mu, rs, ln1_w, ln1_b, Y3);

  // c_attn: (16384,1024,1024) -> 64x4 = 256 blocks
  k_gemm8<0><<<dim3(256), b512, 0, stream>>>(Y3, WAb, Wb, nullptr,
                                             1024, 1024, 1024, 1024, 4);

  // TSSA elementwise chain
  k_chunksum<false><<<dim3(2048), b128, 0, stream>>>(Wb, nullptr, S);
  k_stageA<<<dim3(2048), b128, 0, stream>>>(Wb, S, temp, dbias, tmp);
  k_softmax_scan<<<dim3(128), b256, 0, stream>>>(tmp, Pi, Pc);
  k_chunksum<true><<<dim3(2048), b128, 0, stream>>>(Wb, Pi, S);
  k_stageC<<<dim3(2048), b128, 0, stream>>>(Wb, S, Pi, Pc, Yb);

  // c_proj (writes into Wb slab, now free)
  bf16* Ab = Wb;
  k_gemm8<0><<<dim3(256), b512, 0, stream>>>(Yb, WPb, Ab, nullptr,
                                             1024, 1024, 1024, 1024, 4);

  // residual 1 (x is (B,C,N); x1 is (B,N,C) fp32)
  k_resid1<<<dim3(16, 16, 16), b256, 0, stream>>>(x, Ab, g1, x1);

  // LN2 -> Y4 (reuse Y3 slab)
  k_ln2<<<dim3(16384), b256, 0, stream>>>(x1, ln2_w, ln2_b, Y3);

  // MLP chunked over hidden dim F (2 x 2048); H-half overlays dead [Wb|Yb].
  bf16* Hb = Wb;
  for (int f = 0; f < 2; ++f){
    // up: (16384,2048,1024) -> 64x8 = 512 blocks
    k_gemm8<1><<<dim3(512), b512, 0, stream>>>(Y3, W1b + (size_t)f*2048*1024, Hb,
                                               b1 + f*2048, 1024, 1024, 1024, 2048, 8);
    // down: (16384,1024,2048) -> 256 blocks; f=1 accumulates + bias
    if (f == 0)
      k_gemm8<0><<<dim3(256), b512, 0, stream>>>(Hb, W2b + f*2048, Mb, nullptr,
                                                 2048, 2048, 4096, 1024, 4);
    else
      k_gemm8<3><<<dim3(256), b512, 0, stream>>>(Hb, W2b + f*2048, Mb, b2,
                                                 2048, 2048, 4096, 1024, 4);
  }

  // residual 2 + transpose to (B,C,H,W)
  k_resid2<<<dim3(16, 16, 16), b256, 0, stream>>>(x1, Mb, g2, out);
}